// Round 5
// baseline (1462.100 us; speedup 1.0000x reference)
//
#include <hip/hip_runtime.h>
#include <hip/hip_fp16.h>

// AGCRN: B=32 T=12 N=1024 C=2 D=16 H=64 K=2 OUT=12
// Node-major activations [n][(b,f)], fp16 on GEMM paths; h fp32 master + fp16 mirror.
// Cross-layer software pipeline: per loop iter t handles layer1(t) + layer0(t+1):
//   G1: A@[h1(t)|h2(t-1)] -> YBD     F1: gate1(t)+gate0(t+1)
//   G2: A@[zh1(t)|zh0(t+1)] -> YCE   F2: upd1(t)+upd0(t+1)
// Round 14: depth-4 weight pipeline in F kernels. 4 LDS chunk buffers, ONE barrier per
// chunk (4-buffer rotation removes the write-after-read barrier), chunk kc+3 issued at the
// top of iteration kc (3-chunk lead instead of 1). Counted vmcnt keeps 2 chunks in flight
// across barriers. Weight values & accumulation orders unchanged.

typedef _Float16 f16x8 __attribute__((ext_vector_type(8)));
typedef _Float16 f16x4 __attribute__((ext_vector_type(4)));
typedef float f32x4 __attribute__((ext_vector_type(4)));

#define WAIT_VM0 asm volatile("s_waitcnt vmcnt(0)" ::: "memory")
#define WAIT_VM1 asm volatile("s_waitcnt vmcnt(1)" ::: "memory")
#define WAIT_VM2 asm volatile("s_waitcnt vmcnt(2)" ::: "memory")
#define WAIT_VM4 asm volatile("s_waitcnt vmcnt(4)" ::: "memory")
#define WAIT_VM2_LG asm volatile("s_waitcnt vmcnt(2) lgkmcnt(0)" ::: "memory")
#define WAIT_VM4_LG asm volatile("s_waitcnt vmcnt(4) lgkmcnt(0)" ::: "memory")
#define WAIT_LG asm volatile("s_waitcnt lgkmcnt(0)" ::: "memory")
#define BARRIER do { __builtin_amdgcn_s_barrier(); asm volatile("" ::: "memory"); } while (0)

// ---- weight-chunk DMA. Chunk kc of node n stored contiguously in LDS flat-slot order:
// flat = (o&7) | ((s^(o&3))<<3) | ((o>>3)<<5), 16B per slot. G chunks 8KB, U chunks 4KB.
__device__ __forceinline__ void gload_lds16(const void* g, void* l) {
  __builtin_amdgcn_global_load_lds(
      (const __attribute__((address_space(1))) void*)g,
      (__attribute__((address_space(3))) void*)l, 16, 0, 0);
}

__device__ __forceinline__ void dma_g128(const _Float16* Wc, _Float16* buf, int tid) {
  int wave = tid >> 6;
#pragma unroll
  for (int u = 0; u < 2; ++u) {
    gload_lds16(Wc + (size_t)(u * 256 + tid) * 8,
                buf + (size_t)(u * 256 + wave * 64) * 8);
  }
}

__device__ __forceinline__ void dma_g64(const _Float16* Wc, _Float16* buf, int tid) {
  int wave = tid >> 6;
  gload_lds16(Wc + (size_t)tid * 8, buf + (size_t)(wave * 64) * 8);
}

__device__ __forceinline__ f16x8 wrd(const _Float16* buf, int o, int s) {
  int flat = (o & 7) | (((s ^ (o & 3)) & 3) << 3) | ((o >> 3) << 5);
  return *(const f16x8*)(buf + flat * 8);
}

// ---------------- A = softmax(relu(E E^T)) -> fp16 ----------------
__global__ __launch_bounds__(256) void compute_A_kernel(const float* __restrict__ E,
                                                        __half* __restrict__ Ah) {
  int n = blockIdx.x;
  int tid = threadIdx.x;
  __shared__ float red[256];
  float en[16];
#pragma unroll
  for (int d = 0; d < 16; ++d) en[d] = E[n * 16 + d];
  float v[4];
#pragma unroll
  for (int q = 0; q < 4; ++q) {
    int m = tid + q * 256;
    const float* Em = E + m * 16;
    float dot = 0.f;
#pragma unroll
    for (int d = 0; d < 16; ++d) dot += en[d] * Em[d];
    v[q] = fmaxf(dot, 0.f);
  }
  float mx = fmaxf(fmaxf(v[0], v[1]), fmaxf(v[2], v[3]));
  red[tid] = mx; __syncthreads();
  for (int s = 128; s > 0; s >>= 1) { if (tid < s) red[tid] = fmaxf(red[tid], red[tid + s]); __syncthreads(); }
  mx = red[0];
  __syncthreads();
  float e[4], sum = 0.f;
#pragma unroll
  for (int q = 0; q < 4; ++q) { e[q] = expf(v[q] - mx); sum += e[q]; }
  red[tid] = sum; __syncthreads();
  for (int s = 128; s > 0; s >>= 1) { if (tid < s) red[tid] += red[tid + s]; __syncthreads(); }
  float inv = 1.f / red[0];
#pragma unroll
  for (int q = 0; q < 4; ++q) Ah[(size_t)n * 1024 + tid + q * 256] = __float2half(e[q] * inv);
}

// ---------------- poolT16[j][d]: K-contiguous fp16 pool, coalesced transpose ----------------
__global__ __launch_bounds__(256) void pool_t16_kernel(const float* __restrict__ gw0,
                                                       const float* __restrict__ uw0,
                                                       const float* __restrict__ gw1,
                                                       const float* __restrict__ uw1,
                                                       __half* __restrict__ poolT16) {
  int rg = blockIdx.x;  // 0..831
  const float* pool; int F, Fp, O; size_t jbase; int kk, jj;
  if (rg < 160)      { pool = gw0; F = 66;  Fp = 80;  O = 128; jbase = 0;     kk = rg / 80;          jj = rg % 80; }
  else if (rg < 320) { pool = uw0; F = 66;  Fp = 80;  O = 64;  jbase = 20480; kk = (rg - 160) / 80;  jj = (rg - 160) % 80; }
  else if (rg < 576) { pool = gw1; F = 128; Fp = 128; O = 128; jbase = 30720; kk = (rg - 320) / 128; jj = (rg - 320) % 128; }
  else               { pool = uw1; F = 128; Fp = 128; O = 64;  jbase = 63488; kk = (rg - 576) / 128; jj = (rg - 576) % 128; }
  int o = threadIdx.x;
  if (o >= O) return;
  int i;
  if (F == Fp) i = jj;
  else i = (jj < 64) ? jj + 2 : (jj < 66 ? jj - 64 : -1);
  f16x8 a = {}, b = {}, zz = {};
  if (i >= 0) {
#pragma unroll
    for (int d = 0; d < 8; ++d)
      a[d] = (_Float16)pool[(((size_t)d * 2 + kk) * F + i) * O + o];
#pragma unroll
    for (int d = 8; d < 16; ++d)
      b[d - 8] = (_Float16)pool[(((size_t)d * 2 + kk) * F + i) * O + o];
  }
  size_t j = jbase + (size_t)o * (2 * Fp) + (size_t)kk * Fp + jj;
  _Float16* outp = (_Float16*)poolT16 + j * 32;
  *(f16x8*)outp = a;
  *(f16x8*)(outp + 8) = b;
  *(f16x8*)(outp + 16) = zz;
  *(f16x8*)(outp + 24) = zz;
}

// ---------------- fused prelude: zero-init + x16 + merged biases + E16 ----------------
__global__ __launch_bounds__(256) void prelude_misc_kernel(
    const float* __restrict__ E, __half* __restrict__ E16,
    const float* __restrict__ gb0, const float* __restrict__ ub0,
    const float* __restrict__ gb1, const float* __restrict__ ub1,
    float* __restrict__ Bg0, float* __restrict__ Bu0,
    float* __restrict__ Bg1, float* __restrict__ Bu1,
    const float* __restrict__ src, __half* __restrict__ x16,
    float4* __restrict__ zero_p) {
  int bid = blockIdx.x;
  if (bid < 8192) {
    int i = bid * 256 + threadIdx.x;
    zero_p[i] = float4{0.f, 0.f, 0.f, 0.f};
    return;
  }
  bid -= 8192;
  if (bid < 384) {
    int t0 = bid >> 5, b = bid & 31;
    const float* s = src + (size_t)(b * 12 + t0) * 2048;
    __half* dst = x16 + t0 * 64 + b * 2;
    for (int nn = threadIdx.x; nn < 1024; nn += 256) {
      float2 v = *(const float2*)(s + nn * 2);
      *(__half2*)(dst + (size_t)nn * 768) = __floats2half2_rn(v.x, v.y);
    }
    return;
  }
  bid -= 384;
  if (bid < 1536) {
    int tid = bid * 256 + threadIdx.x;
    if (tid >= 1024 * 384) return;
    int n = tid / 384, c = tid - n * 384;
    const float* pool; float* outp; int O, o;
    if (c < 128)      { pool = gb0; outp = Bg0; O = 128; o = c; }
    else if (c < 192) { pool = ub0; outp = Bu0; O = 64;  o = c - 128; }
    else if (c < 320) { pool = gb1; outp = Bg1; O = 128; o = c - 192; }
    else              { pool = ub1; outp = Bu1; O = 64;  o = c - 320; }
    const float* En = E + n * 16;
    float a = 0.f;
#pragma unroll
    for (int d = 0; d < 16; ++d) a += En[d] * pool[d * O + o];
    outp[n * O + o] = a;
    return;
  }
  bid -= 1536;
  {
    int t = bid * 256 + threadIdx.x;
    if (t >= 1024 * 32) return;
    int d = t & 31;
    E16[t] = (d < 16) ? __float2half(E[(t >> 5) * 16 + d]) : __half(0);
  }
}

// ---------------- Wt via MFMA -> chunk-major pre-swizzled layout, contiguous writes -------
__global__ __launch_bounds__(256) void make_wt_mfma_kernel(
    const __half* __restrict__ E16g, const __half* __restrict__ poolT16g,
    __half* __restrict__ WtG0, __half* __restrict__ WtU0,
    __half* __restrict__ WtG1, __half* __restrict__ WtU1) {
  __shared__ __align__(16) _Float16 Es[64][40];
  __shared__ __align__(16) _Float16 wbuf[64][264];
  const _Float16* E16 = (const _Float16*)E16g;
  const _Float16* pT = (const _Float16*)poolT16g;
  int bx = blockIdx.x;
  __half* Wt; int O, KIP, segbase, kc, og;
  if (bx < 80)       { Wt = WtG0; O = 128; KIP = 160; segbase = 0;     kc = bx % 5;          og = bx / 5; }
  else if (bx < 120) { Wt = WtU0; O = 64;  KIP = 160; segbase = 20480; kc = (bx - 80) % 5;   og = (bx - 80) / 5; }
  else if (bx < 248) { Wt = WtG1; O = 128; KIP = 256; segbase = 30720; kc = (bx - 120) % 8;  og = (bx - 120) / 8; }
  else               { Wt = WtU1; O = 64;  KIP = 256; segbase = 63488; kc = (bx - 248) % 8;  og = (bx - 248) / 8; }
  int o0 = og * 8;
  int n0 = blockIdx.y * 64;
  {
    int r = threadIdx.x >> 2, ch = (threadIdx.x & 3) * 8;
    *(f16x8*)&Es[r][ch] = *(const f16x8*)(E16 + (size_t)(n0 + r) * 32 + ch);
  }
  __syncthreads();
  int wave = threadIdx.x >> 6, lane = threadIdx.x & 63;
  int fm = lane & 15, fg = lane >> 4;
  f16x8 af[4];
#pragma unroll
  for (int i = 0; i < 4; ++i) af[i] = *(const f16x8*)&Es[i * 16 + fm][fg * 8];
  f32x4 acc[4][4] = {};
#pragma unroll
  for (int jt = 0; jt < 4; ++jt) {
    int local = wave * 64 + jt * 16 + fm;       // 0..255
    int oo = local >> 5, kip = local & 31;
    size_t jc = (size_t)segbase + (size_t)(o0 + oo) * KIP + kc * 32 + kip;
    f16x8 bf = *(const f16x8*)(pT + jc * 32 + fg * 8);
#pragma unroll
    for (int i = 0; i < 4; ++i)
      acc[i][jt] = __builtin_amdgcn_mfma_f32_16x16x32_f16(af[i], bf, acc[i][jt], 0, 0, 0);
  }
#pragma unroll
  for (int i = 0; i < 4; ++i)
#pragma unroll
    for (int jt = 0; jt < 4; ++jt)
#pragma unroll
      for (int r = 0; r < 4; ++r)
        wbuf[i * 16 + fg * 4 + r][wave * 64 + jt * 16 + fm] = (_Float16)acc[i][jt][r];
  __syncthreads();
  int NCH = KIP >> 5;            // chunks per node
  int CH = O * 32;               // halves per chunk
  int sbase = (o0 >> 3) * 256;   // this block's half-offset within the chunk
  for (int idx = threadIdx.x; idx < 64 * 32; idx += 256) {
    int nsub = idx >> 5, w = idx & 31;          // w = slot within our 32-slot run
    int oo = w & 7;
    int s = (w >> 3) ^ (w & 3);                 // o0%8==0 so o&3 == w&3
    int pos = oo * 32 + s * 8;                  // local j of this float4's 8 elems
    size_t dst = ((size_t)(n0 + nsub) * NCH + kc) * CH + sbase + (size_t)w * 8;
    *(float4*)(Wt + dst) = *(float4*)&wbuf[nsub][pos];
  }
}

// ---------------- gemm_nt: Y[1024 x Nc] = Ah @ X (64x64 tile) — prelude Axt ----
__global__ __launch_bounds__(256) void gemm_nt_kernel(
    const __half* __restrict__ Ahg, const __half* __restrict__ X0g,
    const __half* __restrict__ X1g, __half* __restrict__ Yg,
    int Nc, int cstride, int split) {
  __shared__ __align__(16) _Float16 As[64][136];
  __shared__ __align__(16) _Float16 Bs[64][144];
  const _Float16* __restrict__ Ah = (const _Float16*)Ahg;
  _Float16* __restrict__ Y = (_Float16*)Yg;
  int tid = threadIdx.x;
  int row0 = blockIdx.y * 64;
  int col0 = blockIdx.x * 64;
  const _Float16* __restrict__ Xsrc =
      (col0 < split) ? (const _Float16*)X0g : (const _Float16*)X1g;
  int colg = (col0 < split) ? col0 : col0 - split;
  int wave = tid >> 6, lane = tid & 63;
  int wm = wave & 1, wn = wave >> 1;
  int fm = lane & 15, fg = lane >> 4;

  int sr = tid >> 2, sc = (tid & 3) * 32;
  const _Float16* pa = Ah + (size_t)(row0 + sr) * 1024 + sc;
  int kq = tid & 31, cg = tid >> 5;
  int kb = 4 * kq;
  const _Float16* pb = Xsrc + (size_t)kb * cstride + colg + cg * 8;
  int chunk = kq >> 1;
  int kin = (kq & 1) * 4;

  f16x8 ra[4], rb[4];
#pragma unroll
  for (int c = 0; c < 4; ++c) ra[c] = *(const f16x8*)(pa + c * 8);
#pragma unroll
  for (int r = 0; r < 4; ++r) rb[r] = *(const f16x8*)(pb + (size_t)r * cstride);

  f32x4 acc[2][2] = {};
  for (int k0 = 0; k0 < 1024; k0 += 128) {
#pragma unroll
    for (int c = 0; c < 4; ++c) *(f16x8*)&As[sr][sc + c * 8] = ra[c];
#pragma unroll
    for (int i = 0; i < 8; ++i) {
      int c = cg * 8 + i;
      f16x4 p;
      p[0] = rb[0][i]; p[1] = rb[1][i]; p[2] = rb[2][i]; p[3] = rb[3][i];
      *(f16x4*)&Bs[c][((chunk ^ (c & 7)) << 3) + kin] = p;
    }
    __syncthreads();
    if (k0 + 128 < 1024) {
#pragma unroll
      for (int c = 0; c < 4; ++c) ra[c] = *(const f16x8*)(pa + k0 + 128 + c * 8);
#pragma unroll
      for (int r = 0; r < 4; ++r)
        rb[r] = *(const f16x8*)(pb + (size_t)(k0 + 128 + r) * cstride);
    }
#pragma unroll
    for (int kc = 0; kc < 4; ++kc) {
      int ck = kc * 4 + fg;
      f16x8 af[2], bf[2];
#pragma unroll
      for (int i = 0; i < 2; ++i)
        af[i] = *(const f16x8*)&As[wm * 32 + i * 16 + fm][kc * 32 + fg * 8];
#pragma unroll
      for (int j = 0; j < 2; ++j) {
        int cl = wn * 32 + j * 16 + fm;
        bf[j] = *(const f16x8*)&Bs[cl][(ck ^ (cl & 7)) << 3];
      }
#pragma unroll
      for (int i = 0; i < 2; ++i)
#pragma unroll
        for (int j = 0; j < 2; ++j)
          acc[i][j] = __builtin_amdgcn_mfma_f32_16x16x32_f16(af[i], bf[j], acc[i][j], 0, 0, 0);
    }
    __syncthreads();
  }
#pragma unroll
  for (int i = 0; i < 2; ++i) {
#pragma unroll
    for (int j = 0; j < 2; ++j) {
      int col = col0 + wn * 32 + j * 16 + fm;
      int rbase = row0 + wm * 32 + i * 16 + fg * 4;
#pragma unroll
      for (int r = 0; r < 4; ++r)
        Y[(size_t)(rbase + r) * Nc + col] = (_Float16)acc[i][j][r];
    }
  }
}

// ---------------- gemm_nt128: Y = Ah @ X, 64(M) x 128(N) tile, K=128/stage ----------------
__global__ __launch_bounds__(256) void gemm_nt128_kernel(
    const __half* __restrict__ Ahg, const __half* __restrict__ X0g,
    const __half* __restrict__ X1g, __half* __restrict__ Yg,
    int Nc, int cstride, int split) {
  __shared__ __align__(16) _Float16 As[64][136];
  __shared__ __align__(16) _Float16 Bs[128][144];
  const _Float16* __restrict__ Ah = (const _Float16*)Ahg;
  _Float16* __restrict__ Y = (_Float16*)Yg;
  int tid = threadIdx.x;
  int row0 = blockIdx.y * 64;
  int col0 = blockIdx.x * 128;
  const _Float16* __restrict__ Xsrc =
      (col0 < split) ? (const _Float16*)X0g : (const _Float16*)X1g;
  int colg = (col0 < split) ? col0 : col0 - split;
  int wave = tid >> 6, lane = tid & 63;
  int fm = lane & 15, fg = lane >> 4;

  int sr = tid >> 2, sc = (tid & 3) * 32;
  const _Float16* pa = Ah + (size_t)(row0 + sr) * 1024 + sc;
  int kq = tid & 31, cg = tid >> 5;
  int kb = 4 * kq;
  const _Float16* pb = Xsrc + (size_t)kb * cstride + colg + cg * 16;
  int chunk = kq >> 1;
  int kin = (kq & 1) * 4;

  f16x8 ra[4], rb[4][2];
#pragma unroll
  for (int c = 0; c < 4; ++c) ra[c] = *(const f16x8*)(pa + c * 8);
#pragma unroll
  for (int r = 0; r < 4; ++r)
#pragma unroll
    for (int h = 0; h < 2; ++h)
      rb[r][h] = *(const f16x8*)(pb + (size_t)r * cstride + h * 8);

  f32x4 acc[4][2] = {};
  for (int k0 = 0; k0 < 1024; k0 += 128) {
#pragma unroll
    for (int c = 0; c < 4; ++c) *(f16x8*)&As[sr][sc + c * 8] = ra[c];
#pragma unroll
    for (int h = 0; h < 2; ++h)
#pragma unroll
      for (int i = 0; i < 8; ++i) {
        int c = cg * 16 + h * 8 + i;
        f16x4 p;
        p[0] = rb[0][h][i]; p[1] = rb[1][h][i]; p[2] = rb[2][h][i]; p[3] = rb[3][h][i];
        *(f16x4*)&Bs[c][((chunk ^ (c & 7)) << 3) + kin] = p;
      }
    __syncthreads();
    if (k0 + 128 < 1024) {
#pragma unroll
      for (int c = 0; c < 4; ++c) ra[c] = *(const f16x8*)(pa + k0 + 128 + c * 8);
#pragma unroll
      for (int r = 0; r < 4; ++r)
#pragma unroll
        for (int h = 0; h < 2; ++h)
          rb[r][h] = *(const f16x8*)(pb + (size_t)(k0 + 128 + r) * cstride + h * 8);
    }
#pragma unroll
    for (int kc = 0; kc < 4; ++kc) {
      int ck = kc * 4 + fg;
      f16x8 af[4], bf[2];
#pragma unroll
      for (int i = 0; i < 4; ++i)
        af[i] = *(const f16x8*)&As[i * 16 + fm][kc * 32 + fg * 8];
#pragma unroll
      for (int j = 0; j < 2; ++j) {
        int cl = wave * 32 + j * 16 + fm;
        bf[j] = *(const f16x8*)&Bs[cl][(ck ^ (cl & 7)) << 3];
      }
#pragma unroll
      for (int i = 0; i < 4; ++i)
#pragma unroll
        for (int j = 0; j < 2; ++j)
          acc[i][j] = __builtin_amdgcn_mfma_f32_16x16x32_f16(af[i], bf[j], acc[i][j], 0, 0, 0);
    }
    __syncthreads();
  }
#pragma unroll
  for (int i = 0; i < 4; ++i) {
#pragma unroll
    for (int j = 0; j < 2; ++j) {
      int col = col0 + wave * 32 + j * 16 + fm;
      int rbase = row0 + i * 16 + fg * 4;
#pragma unroll
      for (int r = 0; r < 4; ++r)
        Y[(size_t)(rbase + r) * Nc + col] = (_Float16)acc[i][j][r];
    }
  }
}

// ---------------- staging-source helpers for F-kernel phase-2 prefetch (T14) ----------------
__device__ __forceinline__ f16x8 ld_g0(const __half* __restrict__ h16,
                                       const __half* __restrict__ YBD, int n, int idx) {
  int b = idx >> 4, part = (idx >> 3) & 1, ch = idx & 7;
  const _Float16* s = part ? (const _Float16*)YBD + (size_t)n * 4096 + b * 64 + ch * 8
                           : (const _Float16*)h16 + (size_t)n * 2048 + b * 64 + ch * 8;
  return *(const f16x8*)s;
}
__device__ __forceinline__ f16x8 ld_u0(const __half* __restrict__ zh0,
                                       const __half* __restrict__ YCE, int n, int idx) {
  int b = idx >> 4, part = (idx >> 3) & 1, ch = idx & 7;
  const _Float16* s = part ? (const _Float16*)YCE + (size_t)n * 4096 + 2048 + b * 64 + ch * 8
                           : (const _Float16*)zh0 + (size_t)n * 2048 + b * 64 + ch * 8;
  return *(const f16x8*)s;
}

// ---------------- gate0 body: depth-4 pipeline; chunks 0,1,2 pre-issued by caller --------
// Wn = chunk-major base for node n; chunk stride 4096 halves (O=128). Buffer idx = kc&3
// (works fused too since the gate1 phase spans 8 chunks, 8 % 4 == 0).
__device__ __forceinline__ void gate0_body(
    _Float16* Xs, _Float16 (*Wb)[4096], int n, int t,
    f16x8 pre0, f16x8 pre1, float2 xv, unsigned axu,
    const _Float16* Wn, const float* __restrict__ Bg,
    const float* __restrict__ h32, __half* __restrict__ zh0, __half* __restrict__ r0) {
  constexpr int STRIDE = 168;
  WAIT_LG;      // own ds ops drained
  BARRIER;      // all waves past phase-1 Xs reads before restaging
  {
    int b0 = t >> 4, p0 = (t >> 3) & 1, c0 = t & 7;
    *(f16x8*)&Xs[b0 * STRIDE + p0 * 80 + c0 * 8] = pre0;
    int idx = t + 256;
    int b1 = idx >> 4, p1 = (idx >> 3) & 1, c1 = idx & 7;
    *(f16x8*)&Xs[b1 * STRIDE + p1 * 80 + c1 * 8] = pre1;
  }
  if (t < 32) {
    Xs[t * STRIDE + 64] = (_Float16)xv.x;
    Xs[t * STRIDE + 65] = (_Float16)xv.y;
    *(unsigned*)&Xs[t * STRIDE + 144] = axu;
  }
  for (int idx = t; idx < 896; idx += 256) {
    int b = idx / 28, jj = idx % 28;
    int col = (jj < 14) ? 66 + jj : 132 + jj;
    Xs[b * STRIDE + col] = (_Float16)0.f;
  }
  int wave = t >> 6, lane = t & 63;
  int fm = lane & 15, fg = lane >> 4;
  f32x4 acc[2][2] = {};
#pragma unroll
  for (int kc = 0; kc < 5; ++kc) {
    if (kc == 0) WAIT_VM4_LG;
    else if (kc < 3) WAIT_VM4;
    else if (kc == 3) WAIT_VM2;
    else WAIT_VM0;
    BARRIER;
    if (kc < 2) dma_g128(Wn + (size_t)(kc + 3) * 4096, Wb[(kc + 3) & 3], t);
    const _Float16* wb = Wb[kc & 3];
    f16x8 af[2], bf[2];
#pragma unroll
    for (int i = 0; i < 2; ++i)
      af[i] = *(const f16x8*)&Xs[(i * 16 + fm) * STRIDE + kc * 32 + fg * 8];
#pragma unroll
    for (int j = 0; j < 2; ++j)
      bf[j] = wrd(wb, wave * 32 + j * 16 + fm, fg);
    __builtin_amdgcn_s_setprio(1);
#pragma unroll
    for (int i = 0; i < 2; ++i)
#pragma unroll
      for (int j = 0; j < 2; ++j)
        acc[i][j] = __builtin_amdgcn_mfma_f32_16x16x32_f16(af[i], bf[j], acc[i][j], 0, 0, 0);
    __builtin_amdgcn_s_setprio(0);
  }
  const float* Bn = Bg + n * 128;
#pragma unroll
  for (int j = 0; j < 2; ++j) {
    int o = wave * 32 + j * 16 + fm;
    float bias = Bn[o];
#pragma unroll
    for (int i = 0; i < 2; ++i)
#pragma unroll
      for (int r = 0; r < 4; ++r) {
        int b = i * 16 + fg * 4 + r;
        float s = 1.f / (1.f + __expf(-(acc[i][j][r] + bias)));
        size_t base = (size_t)n * 2048 + b * 64;
        if (o < 64) zh0[base + o] = __float2half(s * h32[base + o]);
        else        r0[base + o - 64] = __float2half(s);
      }
  }
}

// ---------------- upd0 body: depth-4 pipeline; chunk stride 2048 (O=64) ----------
__device__ __forceinline__ void upd0_body(
    _Float16* Xs, _Float16 (*Wb)[2048], int n, int t,
    f16x8 pre0, f16x8 pre1, float2 xv, unsigned axu,
    const _Float16* Wn, const float* __restrict__ Bu,
    const __half* __restrict__ r0, float* __restrict__ h32, __half* __restrict__ h16) {
  constexpr int STRIDE = 168;
  WAIT_LG;
  BARRIER;
  {
    int b0 = t >> 4, p0 = (t >> 3) & 1, c0 = t & 7;
    *(f16x8*)&Xs[b0 * STRIDE + p0 * 80 + c0 * 8] = pre0;
    int idx = t + 256;
    int b1 = idx >> 4, p1 = (idx >> 3) & 1, c1 = idx & 7;
    *(f16x8*)&Xs[b1 * STRIDE + p1 * 80 + c1 * 8] = pre1;
  }
  if (t < 32) {
    Xs[t * STRIDE + 64] = (_Float16)xv.x;
    Xs[t * STRIDE + 65] = (_Float16)xv.y;
    *(unsigned*)&Xs[t * STRIDE + 144] = axu;
  }
  for (int idx = t; idx < 896; idx += 256) {
    int b = idx / 28, jj = idx % 28;
    int col = (jj < 14) ? 66 + jj : 132 + jj;
    Xs[b * STRIDE + col] = (_Float16)0.f;
  }
  int wave = t >> 6, lane = t & 63;
  int fm = lane & 15, fg = lane >> 4;
  f32x4 acc[2] = {};
#pragma unroll
  for (int kc = 0; kc < 5; ++kc) {
    if (kc == 0) WAIT_VM2_LG;
    else if (kc < 3) WAIT_VM2;
    else if (kc == 3) WAIT_VM1;
    else WAIT_VM0;
    BARRIER;
    if (kc < 2) dma_g64(Wn + (size_t)(kc + 3) * 2048, Wb[(kc + 3) & 3], t);
    const _Float16* wb = Wb[kc & 3];
    f16x8 bf = wrd(wb, wave * 16 + fm, fg);
    f16x8 af0 = *(const f16x8*)&Xs[(0 * 16 + fm) * STRIDE + kc * 32 + fg * 8];
    f16x8 af1 = *(const f16x8*)&Xs[(1 * 16 + fm) * STRIDE + kc * 32 + fg * 8];
    __builtin_amdgcn_s_setprio(1);
    acc[0] = __builtin_amdgcn_mfma_f32_16x16x32_f16(af0, bf, acc[0], 0, 0, 0);
    acc[1] = __builtin_amdgcn_mfma_f32_16x16x32_f16(af1, bf, acc[1], 0, 0, 0);
    __builtin_amdgcn_s_setprio(0);
  }
  int o = wave * 16 + fm;
  float bias = Bu[n * 64 + o];
#pragma unroll
  for (int i = 0; i < 2; ++i)
#pragma unroll
    for (int r = 0; r < 4; ++r) {
      int b = i * 16 + fg * 4 + r;
      float x = acc[i][r] + bias;
      x = fminf(fmaxf(x, -15.f), 15.f);
      float e = __expf(2.f * x);
      float hc = (e - 1.f) / (e + 1.f);
      size_t base = (size_t)n * 2048 + b * 64;
      float rr = __half2float(r0[base + o]);
      float hnew = rr * h32[base + o] + (1.f - rr) * hc;
      h32[base + o] = hnew;
      h16[base + o] = __float2half(hnew);
    }
}

// ---------------- standalone gate0 / upd0 (prologue) ----------------
__global__ __launch_bounds__(256) void gate0_kernel(
    const __half* __restrict__ h16, const __half* __restrict__ YBD,
    const float* __restrict__ src, const __half* __restrict__ Axt, int tstep,
    const __half* __restrict__ Wtg, const float* __restrict__ Bg,
    const float* __restrict__ h32, __half* __restrict__ zh0, __half* __restrict__ r0) {
  __shared__ __align__(16) _Float16 Xs[32 * 168];
  __shared__ __align__(16) _Float16 Wb[4][4096];
  int n = blockIdx.x, t = threadIdx.x;
  const _Float16* Wn = (const _Float16*)Wtg + (size_t)n * 20480;  // 5 chunks * 4096
  f16x8 p0 = ld_g0(h16, YBD, n, t);
  f16x8 p1 = ld_g0(h16, YBD, n, t + 256);
  float2 xv = {}; unsigned ax = 0;
  if (t < 32) {
    xv = *(const float2*)(src + ((size_t)(t * 12 + tstep) * 1024 + n) * 2);
    ax = *(const unsigned*)((const _Float16*)Axt + (size_t)n * 768 + tstep * 64 + t * 2);
  }
  dma_g128(Wn, Wb[0], t);
  dma_g128(Wn + 4096, Wb[1], t);
  dma_g128(Wn + 8192, Wb[2], t);
  gate0_body(Xs, Wb, n, t, p0, p1, xv, ax, Wn, Bg, h32, zh0, r0);
}

__global__ __launch_bounds__(256) void upd0_kernel(
    const __half* __restrict__ zh0, const __half* __restrict__ YCE,
    const float* __restrict__ src, const __half* __restrict__ Axt, int tstep,
    const __half* __restrict__ Wtg, const float* __restrict__ Bu,
    const __half* __restrict__ r0, float* __restrict__ h32, __half* __restrict__ h16) {
  __shared__ __align__(16) _Float16 Xs[32 * 168];
  __shared__ __align__(16) _Float16 Wb[4][2048];
  int n = blockIdx.x, t = threadIdx.x;
  const _Float16* Wn = (const _Float16*)Wtg + (size_t)n * 10240;  // 5 chunks * 2048
  f16x8 p0 = ld_u0(zh0, YCE, n, t);
  f16x8 p1 = ld_u0(zh0, YCE, n, t + 256);
  float2 xv = {}; unsigned ax = 0;
  if (t < 32) {
    xv = *(const float2*)(src + ((size_t)(t * 12 + tstep) * 1024 + n) * 2);
    ax = *(const unsigned*)((const _Float16*)Axt + (size_t)n * 768 + tstep * 64 + t * 2);
  }
  dma_g64(Wn, Wb[0], t);
  dma_g64(Wn + 2048, Wb[1], t);
  dma_g64(Wn + 4096, Wb[2], t);
  upd0_body(Xs, Wb, n, t, p0, p1, xv, ax, Wn, Bu, r0, h32, h16);
}

// ---------------- F1: gate1(t) + gate0(t+1) ----------------
__global__ __launch_bounds__(256) void gate1_gate0_kernel(
    const __half* __restrict__ h1_16, const __half* __restrict__ h2_16,
    const __half* __restrict__ YBD,
    const __half* __restrict__ WtG1, const float* __restrict__ Bg1,
    const float* __restrict__ h2_32, __half* __restrict__ zh1, __half* __restrict__ r1,
    const float* __restrict__ src, const __half* __restrict__ Axt, int tnext,
    const __half* __restrict__ WtG0, const float* __restrict__ Bg0,
    const float* __restrict__ h1_32, __half* __restrict__ zh0, __half* __restrict__ r0,
    int do_gate0) {
  constexpr int STRIDE = 264;
  __shared__ __align__(16) _Float16 Xs[32 * STRIDE];
  __shared__ __align__(16) _Float16 Wb[4][4096];
  int n = blockIdx.x;
  int t = threadIdx.x;
  const _Float16* Wn1 = (const _Float16*)WtG1 + (size_t)n * 32768;  // 8 chunks * 4096
  const _Float16* Wn0 = (const _Float16*)WtG0 + (size_t)n * 20480;  // 5 chunks * 4096
  // phase-1 staging loads
  f16x8 s1[4];
#pragma unroll
  for (int u = 0; u < 4; ++u) {
    int idx = t + u * 256;
    int b = idx >> 5, q = idx & 31;
    const _Float16* s;
    if (q < 8)       s = (const _Float16*)h1_16 + (size_t)n * 2048 + b * 64 + q * 8;
    else if (q < 16) s = (const _Float16*)h2_16 + (size_t)n * 2048 + b * 64 + (q - 8) * 8;
    else if (q < 24) s = (const _Float16*)YBD + (size_t)n * 4096 + b * 64 + (q - 16) * 8;
    else             s = (const _Float16*)YBD + (size_t)n * 4096 + 2048 + b * 64 + (q - 24) * 8;
    s1[u] = *(const f16x8*)s;
  }
  // phase-2 prefetch (T14)
  f16x8 g0p0 = {}, g0p1 = {}; float2 g0xv = {}; unsigned g0ax = 0;
  if (do_gate0) {
    g0p0 = ld_g0(h1_16, YBD, n, t);
    g0p1 = ld_g0(h1_16, YBD, n, t + 256);
    if (t < 32) {
      g0xv = *(const float2*)(src + ((size_t)(t * 12 + tnext) * 1024 + n) * 2);
      g0ax = *(const unsigned*)((const _Float16*)Axt + (size_t)n * 768 + tnext * 64 + t * 2);
    }
  }
  // phase-1 weight chunks 0,1,2
  dma_g128(Wn1, Wb[0], t);
  dma_g128(Wn1 + 4096, Wb[1], t);
  dma_g128(Wn1 + 8192, Wb[2], t);
#pragma unroll
  for (int u = 0; u < 4; ++u) {
    int idx = t + u * 256;
    int b = idx >> 5, q = idx & 31;
    *(f16x8*)&Xs[b * STRIDE + q * 8] = s1[u];
  }
  int wave = t >> 6, lane = t & 63;
  int fm = lane & 15, fg = lane >> 4;
  {
    f32x4 acc[2][2] = {};
#pragma unroll
    for (int kc = 0; kc < 8; ++kc) {
      if (kc == 0) WAIT_VM4_LG;
      else if (kc < 6) WAIT_VM4;
      else if (kc == 6) { if (do_gate0) WAIT_VM4; else WAIT_VM2; }
      else { if (do_gate0) WAIT_VM4; else WAIT_VM0; }
      BARRIER;
      int g = kc + 3;
      if (g < 8) dma_g128(Wn1 + (size_t)g * 4096, Wb[g & 3], t);
      else if (do_gate0) dma_g128(Wn0 + (size_t)(g - 8) * 4096, Wb[g & 3], t);
      const _Float16* wb = Wb[kc & 3];
      f16x8 af[2], bf[2];
#pragma unroll
      for (int i = 0; i < 2; ++i)
        af[i] = *(const f16x8*)&Xs[(i * 16 + fm) * STRIDE + kc * 32 + fg * 8];
#pragma unroll
      for (int j = 0; j < 2; ++j)
        bf[j] = wrd(wb, wave * 32 + j * 16 + fm, fg);
      __builtin_amdgcn_s_setprio(1);
#pragma unroll
      for (int i = 0; i < 2; ++i)
#pragma unroll
        for (int j = 0; j < 2; ++j)
          acc[i][j] = __builtin_amdgcn_mfma_f32_16x16x32_f16(af[i], bf[j], acc[i][j], 0, 0, 0);
      __builtin_amdgcn_s_setprio(0);
    }
    const float* Bn = Bg1 + n * 128;
#pragma unroll
    for (int j = 0; j < 2; ++j) {
      int o = wave * 32 + j * 16 + fm;
      float bias = Bn[o];
#pragma unroll
      for (int i = 0; i < 2; ++i)
#pragma unroll
        for (int r = 0; r < 4; ++r) {
          int b = i * 16 + fg * 4 + r;
          float s = 1.f / (1.f + __expf(-(acc[i][j][r] + bias)));
          size_t base = (size_t)n * 2048 + b * 64;
          if (o < 64) zh1[base + o] = __float2half(s * h2_32[base + o]);
          else        r1[base + o - 64] = __float2half(s);
        }
    }
  }
  if (!do_gate0) return;
  gate0_body(Xs, Wb, n, t, g0p0, g0p1, g0xv, g0ax, Wn0, Bg0, h1_32, zh0, r0);
}

// ---------------- F2: upd1(t) + upd0(t+1) ----------------
__global__ __launch_bounds__(256) void upd1_upd0_kernel(
    const __half* __restrict__ h1_16, const __half* __restrict__ zh1,
    const __half* __restrict__ YBD, const __half* __restrict__ YCE,
    const __half* __restrict__ WtU1, const float* __restrict__ Bu1,
    const __half* __restrict__ r1, float* __restrict__ h2_32, __half* __restrict__ h2_16,
    const __half* __restrict__ zh0,
    const float* __restrict__ src, const __half* __restrict__ Axt, int tnext,
    const __half* __restrict__ WtU0, const float* __restrict__ Bu0,
    const __half* __restrict__ r0, float* __restrict__ h1_32, __half* __restrict__ h1_16w,
    int do_upd0) {
  constexpr int STRIDE = 264;
  __shared__ __align__(16) _Float16 Xs[32 * STRIDE];
  __shared__ __align__(16) _Float16 Wb[4][2048];
  int n = blockIdx.x;
  int t = threadIdx.x;
  const _Float16* Wn1 = (const _Float16*)WtU1 + (size_t)n * 16384;  // 8 chunks * 2048
  const _Float16* Wn0 = (const _Float16*)WtU0 + (size_t)n * 10240;  // 5 chunks * 2048
  // phase-1 staging loads
  f16x8 s1[4];
#pragma unroll
  for (int u = 0; u < 4; ++u) {
    int idx = t + u * 256;
    int b = idx >> 5, q = idx & 31;
    const _Float16* s;
    if (q < 8)       s = (const _Float16*)h1_16 + (size_t)n * 2048 + b * 64 + q * 8;
    else if (q < 16) s = (const _Float16*)zh1 + (size_t)n * 2048 + b * 64 + (q - 8) * 8;
    else if (q < 24) s = (const _Float16*)YBD + (size_t)n * 4096 + b * 64 + (q - 16) * 8;
    else             s = (const _Float16*)YCE + (size_t)n * 4096 + b * 64 + (q - 24) * 8;
    s1[u] = *(const f16x8*)s;
  }
  // phase-2 prefetch (T14)
  f16x8 u0p0 = {}, u0p1 = {}; float2 u0xv = {}; unsigned u0ax = 0;
  if (do_upd0) {
    u0p0 = ld_u0(zh0, YCE, n, t);
    u0p1 = ld_u0(zh0, YCE, n, t + 256);
    if (t < 32) {
      u0xv = *(const float2*)(src + ((size_t)(t * 12 + tnext) * 1024 + n) * 2);
      u0ax = *(const unsigned*)((const _Float16*)Axt + (size_t)n * 768 + tnext * 64 + t * 2);
    }
  }
  // phase-1 weight chunks 0,1,2
  dma_g64(Wn1, Wb[0], t);
  dma_g64(Wn1 + 2048, Wb[1], t);
  dma_g64(Wn1 + 4096, Wb[2], t);
#pragma unroll
  for (int u = 0; u < 4; ++u) {
    int idx = t + u * 256;
    int b = idx >> 5, q = idx & 31;
    *(f16x8*)&Xs[b * STRIDE + q * 8] = s1[u];
  }
  int wave = t >> 6, lane = t & 63;
  int fm = lane & 15, fg = lane >> 4;
  {
    f32x4 acc[2] = {};
#pragma unroll
    for (int kc = 0; kc < 8; ++kc) {
      if (kc == 0) WAIT_VM2_LG;
      else if (kc < 6) WAIT_VM2;
      else if (kc == 6) { if (do_upd0) WAIT_VM2; else WAIT_VM1; }
      else { if (do_upd0) WAIT_VM2; else WAIT_VM0; }
      BARRIER;
      int g = kc + 3;
      if (g < 8) dma_g64(Wn1 + (size_t)g * 2048, Wb[g & 3], t);
      else if (do_upd0) dma_g64(Wn0 + (size_t)(g - 8) * 2048, Wb[g & 3], t);
      const _Float16* wb = Wb[kc & 3];
      f16x8 bf = wrd(wb, wave * 16 + fm, fg);
      f16x8 af0 = *(const f16x8*)&Xs[(0 * 16 + fm) * STRIDE + kc * 32 + fg * 8];
      f16x8 af1 = *(const f16x8*)&Xs[(1 * 16 + fm) * STRIDE + kc * 32 + fg * 8];
      __builtin_amdgcn_s_setprio(1);
      acc[0] = __builtin_amdgcn_mfma_f32_16x16x32_f16(af0, bf, acc[0], 0, 0, 0);
      acc[1] = __builtin_amdgcn_mfma_f32_16x16x32_f16(af1, bf, acc[1], 0, 0, 0);
      __builtin_amdgcn_s_setprio(0);
    }
    int o = wave * 16 + fm;
    float bias = Bu1[n * 64 + o];
#pragma unroll
    for (int i = 0; i < 2; ++i)
#pragma unroll
      for (int r = 0; r < 4; ++r) {
        int b = i * 16 + fg * 4 + r;
        float x = acc[i][r] + bias;
        x = fminf(fmaxf(x, -15.f), 15.f);
        float e = __expf(2.f * x);
        float hc = (e - 1.f) / (e + 1.f);
        size_t base = (size_t)n * 2048 + b * 64;
        float rr = __half2float(r1[base + o]);
        float hnew = rr * h2_32[base + o] + (1.f - rr) * hc;
        h2_32[base + o] = hnew;
        h2_16[base + o] = __float2half(hnew);
      }
  }
  if (!do_upd0) return;
  upd0_body(Xs, Wb, n, t, u0p0, u0p1, u0xv, u0ax, Wn0, Bu0, r0, h1_32, h1_16w);
}

// ---------------- out[b,o,n] = h2[n,b,:] . conv_w[o,:] + conv_b[o] ----------------
__global__ void final_conv_kernel(const float* __restrict__ h2, const float* __restrict__ cw,
                                  const float* __restrict__ cb, float* __restrict__ out) {
  int tid = blockIdx.x * 256 + threadIdx.x;
  if (tid >= 32 * 1024) return;
  int n = tid & 1023, b = tid >> 10;
  const float* hp = h2 + ((size_t)n * 32 + b) * 64;
  float hv[64];
#pragma unroll
  for (int i = 0; i < 64; ++i) hv[i] = hp[i];
#pragma unroll
  for (int o = 0; o < 12; ++o) {
    float acc = cb[o];
#pragma unroll
    for (int i = 0; i < 64; ++i) acc += hv[i] * cw[o * 64 + i];
    out[((size_t)b * 12 + o) * 1024 + n] = acc;
  }
}

extern "C" void kernel_launch(void* const* d_in, const int* in_sizes, int n_in,
                              void* d_out, int out_size, void* d_ws, size_t ws_size,
                              hipStream_t stream) {
  const float* src = (const float*)d_in[0];
  const float* E   = (const float*)d_in[1];
  const float* gw0 = (const float*)d_in[2];
  const float* gb0 = (const float*)d_in[3];
  const float* uw0 = (const float*)d_in[4];
  const float* ub0 = (const float*)d_in[5];
  const float* gw1 = (const float*)d_in[6];
  const float* gb1 = (const float*)d_in[7];
  const float* uw1 = (const float*)d_in[8];
  const float* ub1 = (const float*)d_in[9];
  const float* cw  = (const float*)d_in[10];
  const float* cb  = (const float*)d_in[11];
  float* out = (float*)d_out;
  (void)in_sizes; (void)n_in; (void)out_size; (void)ws_size;

  char* base = (char*)d_ws;
  size_t off = 0;
  auto alloc = [&](size_t bytes) -> void* {
    void* p = base + off; off += (bytes + 511) & ~(size_t)511; return p;
  };
  __half* Ah   = (__half*)alloc((size_t)1024 * 1024 * 2);           //   2.1 MB
  __half* WtG0 = (__half*)alloc((size_t)1024 * 128 * 160 * 2);      //  41.9 MB
  __half* WtU0 = (__half*)alloc((size_t)1024 * 64 * 160 * 2);       //  21.0 MB
  __half* WtG1 = (__half*)alloc((size_t)1024 * 128 * 256 * 2);      //  67.1 MB
  __half* WtU1 = (__half*)alloc((size_t)1024 * 64 * 256 * 2);       //  33.6 MB
  float*  Bg0  = (float*) alloc((size_t)1024 * 128 * 4);
  float*  Bu0  = (float*) alloc((size_t)1024 * 64 * 4);
  float*  Bg1  = (float*) alloc((size_t)1024 * 128 * 4);
  float*  Bu1  = (float*) alloc((size_t)1024 * 64 * 4);
  // zero-init region (contiguous): h1_32, h2_32, h1_16, h2_16, YBD  (8388608 floats)
  float*  h1_32 = (float*)alloc((size_t)1024 * 2048 * 4);           //   8.4 MB
  float*  h2_32 = (float*)alloc((size_t)1024 * 2048 * 4);           //   8.4 MB
  __half* h1_16 = (__half*)alloc((size_t)1024 * 2048 * 2);          //   4.2 MB
  __half* h2_16 = (__half*)alloc((size_t)1024 * 2048 * 2);          //   4.2 MB
  __half* YBD  = (__half*)alloc((size_t)1024 * 4096 * 2);           //   8.4 MB [A@h1 | A@h2]
  __half* YCE  = (__half*)alloc((size_t)1024 * 4096 * 2);           //   8.4 MB [A@zh1 | A@zh0]
  __half* zh0  = (__half*)alloc((size_t)1024 * 2048 * 2);           //   4.2 MB
  __half* zh1  = (__half*)alloc((size_t)1024 * 2048 * 2);           //   4.2 MB
  __half* Axt  = (__half*)alloc((size_t)1024 * 768 * 2);            //   1.5 MB (A@x all t)
  __half* r1   = (__half*)alloc((size_t)1024 * 2048 * 2);           //   4.2 MB
  __half* r0   = (__half*)alloc((size_t)1024 * 2048 * 2);           //   4.2 MB
  __half* poolT16 = (__half*)alloc((size_t)79872 * 32 * 2);         //   5.1 MB
  __half* E16  = (__half*)alloc((size_t)1024 * 32 * 2);             //  64 KB
  __half* x16  = (__half*)alloc((size_t)1024 * 768 * 2);            //   1.5 MB
  // total ~234 MB

  // ---- prelude (5 dispatches) ----
  compute_A_kernel<<<1024, 256, 0, stream>>>(E, Ah);
  prelude_misc_kernel<<<10240, 256, 0, stream>>>(E, E16, gb0, ub0, gb1, ub1,
                                                 Bg0, Bu0, Bg1, Bu1,
                                                 src, x16, (float4*)h1_32);
  pool_t16_kernel<<<832, 256, 0, stream>>>(gw0, uw0, gw1, uw1, poolT16);
  make_wt_mfma_kernel<<<dim3(312, 16), 256, 0, stream>>>(E16, poolT16, WtG0, WtU0, WtG1, WtU1);
  gemm_nt_kernel<<<dim3(12, 16), 256, 0, stream>>>(Ah, (__half*)x16, (__half*)x16, Axt,
                                                   768, 768, 768);

  // ---- prologue: layer-0 step 0 ----
  gate0_kernel<<<1024, 256, 0, stream>>>(h1_16, YBD, src, Axt, 0, WtG0, Bg0, h1_32, zh0, r0);
  gemm_nt128_kernel<<<dim3(16, 16), 256, 0, stream>>>(Ah, zh0, zh0, YCE + 2048,
                                                      4096, 2048, 2048);  // YE = A@zh0(0)
  upd0_kernel<<<1024, 256, 0, stream>>>(zh0, YCE, src, Axt, 0, WtU0, Bu0, r0, h1_32, h1_16);

  // ---- 12 pipelined iterations (4 dispatches each) ----
  for (int t = 0; t < 12; ++t) {
    int more = (t < 11) ? 1 : 0;
    gemm_nt128_kernel<<<dim3(32, 16), 256, 0, stream>>>(Ah, h1_16, h2_16, YBD,
                                                        4096, 2048, 2048);   // G1
    gate1_gate0_kernel<<<1024, 256, 0, stream>>>(h1_16, h2_16, YBD, WtG1, Bg1, h2_32, zh1, r1,
                                                 src, Axt, t + 1, WtG0, Bg0, h1_32, zh0, r0,
                                                 more);                       // F1
    gemm_nt128_kernel<<<dim3(32, 16), 256, 0, stream>>>(Ah, zh1, zh0, YCE,
                                                        4096, 2048, 2048);   // G2
    upd1_upd0_kernel<<<1024, 256, 0, stream>>>(h1_16, zh1, YBD, YCE, WtU1, Bu1, r1,
                                               h2_32, h2_16, zh0, src, Axt, t + 1,
                                               WtU0, Bu0, r0, h1_32, h1_16, more);  // F2
  }

  final_conv_kernel<<<(32 * 1024 + 255) / 256, 256, 0, stream>>>(h2_32, cw, cb, out);
}

// Round 7
// 1323.912 us; speedup vs baseline: 1.1044x; 1.1044x over previous
//
#include <hip/hip_runtime.h>
#include <hip/hip_fp16.h>

// AGCRN: B=32 T=12 N=1024 C=2 D=16 H=64 K=2 OUT=12
// Node-major activations [n][(b,f)], fp16 on GEMM paths; h fp32 master + fp16 mirror.
// Cross-layer software pipeline: per loop iter t handles layer1(t) + layer0(t+1):
//   G1: A@[h1(t)|h2(t-1)] -> YBD     F1: gate1(t)+gate0(t+1)
//   G2: A@[zh1(t)|zh0(t+1)] -> YCE   F2: upd1(t)+upd0(t+1)
// Round 16: round-15 K=128 fold with the pool_t16 grid bug fixed (768 blocks, not 640 —
// uw1's kk=1 half was never transposed, corrupting WtU1). xq x-values fp16-roundtripped
// to match original staging precision.

typedef _Float16 f16x8 __attribute__((ext_vector_type(8)));
typedef _Float16 f16x4 __attribute__((ext_vector_type(4)));
typedef float f32x4 __attribute__((ext_vector_type(4)));

#define WAIT_VM0 asm volatile("s_waitcnt vmcnt(0)" ::: "memory")
#define WAIT_VM1 asm volatile("s_waitcnt vmcnt(1)" ::: "memory")
#define WAIT_VM2 asm volatile("s_waitcnt vmcnt(2)" ::: "memory")
#define WAIT_VM1_LG asm volatile("s_waitcnt vmcnt(1) lgkmcnt(0)" ::: "memory")
#define WAIT_VM2_LG asm volatile("s_waitcnt vmcnt(2) lgkmcnt(0)" ::: "memory")
#define WAIT_LG asm volatile("s_waitcnt lgkmcnt(0)" ::: "memory")
#define BARRIER do { __builtin_amdgcn_s_barrier(); asm volatile("" ::: "memory"); } while (0)

// ---- weight-chunk DMA. Chunk kc of node n stored contiguously in LDS flat-slot order:
// flat = (o&7) | ((s^(o&3))<<3) | ((o>>3)<<5), 16B per slot. G chunks 8KB, U chunks 4KB.
__device__ __forceinline__ void gload_lds16(const void* g, void* l) {
  __builtin_amdgcn_global_load_lds(
      (const __attribute__((address_space(1))) void*)g,
      (__attribute__((address_space(3))) void*)l, 16, 0, 0);
}

__device__ __forceinline__ void dma_g128(const _Float16* Wc, _Float16* buf, int tid) {
  int wave = tid >> 6;
#pragma unroll
  for (int u = 0; u < 2; ++u) {
    gload_lds16(Wc + (size_t)(u * 256 + tid) * 8,
                buf + (size_t)(u * 256 + wave * 64) * 8);
  }
}

__device__ __forceinline__ void dma_g64(const _Float16* Wc, _Float16* buf, int tid) {
  int wave = tid >> 6;
  gload_lds16(Wc + (size_t)tid * 8, buf + (size_t)(wave * 64) * 8);
}

__device__ __forceinline__ f16x8 wrd(const _Float16* buf, int o, int s) {
  int flat = (o & 7) | (((s ^ (o & 3)) & 3) << 3) | ((o >> 3) << 5);
  return *(const f16x8*)(buf + flat * 8);
}

// ---------------- A = softmax(relu(E E^T)) -> fp16 ----------------
__global__ __launch_bounds__(256) void compute_A_kernel(const float* __restrict__ E,
                                                        __half* __restrict__ Ah) {
  int n = blockIdx.x;
  int tid = threadIdx.x;
  __shared__ float red[256];
  float en[16];
#pragma unroll
  for (int d = 0; d < 16; ++d) en[d] = E[n * 16 + d];
  float v[4];
#pragma unroll
  for (int q = 0; q < 4; ++q) {
    int m = tid + q * 256;
    const float* Em = E + m * 16;
    float dot = 0.f;
#pragma unroll
    for (int d = 0; d < 16; ++d) dot += en[d] * Em[d];
    v[q] = fmaxf(dot, 0.f);
  }
  float mx = fmaxf(fmaxf(v[0], v[1]), fmaxf(v[2], v[3]));
  red[tid] = mx; __syncthreads();
  for (int s = 128; s > 0; s >>= 1) { if (tid < s) red[tid] = fmaxf(red[tid], red[tid + s]); __syncthreads(); }
  mx = red[0];
  __syncthreads();
  float e[4], sum = 0.f;
#pragma unroll
  for (int q = 0; q < 4; ++q) { e[q] = expf(v[q] - mx); sum += e[q]; }
  red[tid] = sum; __syncthreads();
  for (int s = 128; s > 0; s >>= 1) { if (tid < s) red[tid] += red[tid + s]; __syncthreads(); }
  float inv = 1.f / red[0];
#pragma unroll
  for (int q = 0; q < 4; ++q) Ah[(size_t)n * 1024 + tid + q * 256] = __float2half(e[q] * inv);
}

// ---------------- poolT16[j][d]: K-contiguous fp16 pool (h-columns only for layer 0) ------
// Layer-0 segs: j = jb + o*(2*64) + kk*64 + jj, pool i = jj+2 (h starts after x's 2 cols).
// Layer-1 segs: j = jb + o*(2*128) + kk*128 + jj, i = jj.   GRID = 768 blocks.
__global__ __launch_bounds__(256) void pool_t16_kernel(const float* __restrict__ gw0,
                                                       const float* __restrict__ uw0,
                                                       const float* __restrict__ gw1,
                                                       const float* __restrict__ uw1,
                                                       __half* __restrict__ poolT16) {
  int rg = blockIdx.x;  // 0..767
  const float* pool; int F, O, TK; size_t jb; int kk, jj, i;
  if (rg < 128)      { pool = gw0; F = 66;  O = 128; TK = 64;  jb = 0;     kk = rg >> 6; jj = rg & 63; i = jj + 2; }
  else if (rg < 256) { int r = rg - 128; pool = uw0; F = 66;  O = 64;  TK = 64;  jb = 16384; kk = r >> 6; jj = r & 63;  i = jj + 2; }
  else if (rg < 512) { int r = rg - 256; pool = gw1; F = 128; O = 128; TK = 128; jb = 24576; kk = r >> 7; jj = r & 127; i = jj; }
  else               { int r = rg - 512; pool = uw1; F = 128; O = 64;  TK = 128; jb = 57344; kk = r >> 7; jj = r & 127; i = jj; }
  int o = threadIdx.x;
  if (o >= O) return;
  f16x8 a, b, zz = {};
#pragma unroll
  for (int d = 0; d < 8; ++d)
    a[d] = (_Float16)pool[(((size_t)d * 2 + kk) * F + i) * O + o];
#pragma unroll
  for (int d = 8; d < 16; ++d)
    b[d - 8] = (_Float16)pool[(((size_t)d * 2 + kk) * F + i) * O + o];
  size_t j = jb + (size_t)o * (2 * TK) + (size_t)kk * TK + jj;
  _Float16* outp = (_Float16*)poolT16 + j * 32;
  *(f16x8*)outp = a;
  *(f16x8*)(outp + 8) = b;
  *(f16x8*)(outp + 16) = zz;
  *(f16x8*)(outp + 24) = zz;
}

// ---------------- fused prelude: zero + x16 + biases + E16 + Wx coefficients ----------------
__global__ __launch_bounds__(256) void prelude_misc_kernel(
    const float* __restrict__ E, __half* __restrict__ E16,
    const float* __restrict__ gb0, const float* __restrict__ ub0,
    const float* __restrict__ gb1, const float* __restrict__ ub1,
    float* __restrict__ Bg0, float* __restrict__ Bu0,
    float* __restrict__ Bg1, float* __restrict__ Bu1,
    const float* __restrict__ src, __half* __restrict__ x16,
    const float* __restrict__ gw0, const float* __restrict__ uw0,
    float* __restrict__ WxG0, float* __restrict__ WxU0,
    float4* __restrict__ zero_p) {
  int bid = blockIdx.x;
  if (bid < 8192) {
    int i = bid * 256 + threadIdx.x;
    zero_p[i] = float4{0.f, 0.f, 0.f, 0.f};
    return;
  }
  bid -= 8192;
  if (bid < 384) {
    int t0 = bid >> 5, b = bid & 31;
    const float* s = src + (size_t)(b * 12 + t0) * 2048;
    __half* dst = x16 + t0 * 64 + b * 2;
    for (int nn = threadIdx.x; nn < 1024; nn += 256) {
      float2 v = *(const float2*)(s + nn * 2);
      *(__half2*)(dst + (size_t)nn * 768) = __floats2half2_rn(v.x, v.y);
    }
    return;
  }
  bid -= 384;
  if (bid < 1536) {
    int tid = bid * 256 + threadIdx.x;
    if (tid >= 1024 * 384) return;
    int n = tid / 384, c = tid - n * 384;
    const float* pool; float* outp; int O, o;
    if (c < 128)      { pool = gb0; outp = Bg0; O = 128; o = c; }
    else if (c < 192) { pool = ub0; outp = Bu0; O = 64;  o = c - 128; }
    else if (c < 320) { pool = gb1; outp = Bg1; O = 128; o = c - 192; }
    else              { pool = ub1; outp = Bu1; O = 64;  o = c - 320; }
    const float* En = E + n * 16;
    float a = 0.f;
#pragma unroll
    for (int d = 0; d < 16; ++d) a += En[d] * pool[d * O + o];
    outp[n * O + o] = a;
    return;
  }
  bid -= 1536;
  if (bid < 128) {
    int t = bid * 256 + threadIdx.x;
    int d = t & 31;
    E16[t] = (d < 16) ? __float2half(E[(t >> 5) * 16 + d]) : __half(0);
    return;
  }
  bid -= 128;
  if (bid < 2048) {  // WxG0[n][kk*2+c][o] = sum_d E[n,d]*gw0[d][kk][c][o], fp16-rounded
    int v = bid * 256 + threadIdx.x;
    int n = v >> 9, q = (v >> 7) & 3, o = v & 127;
    int kk = q >> 1, c = q & 1;
    const float* En = E + n * 16;
    float a = 0.f;
#pragma unroll
    for (int d = 0; d < 16; ++d)
      a += En[d] * gw0[(((size_t)d * 2 + kk) * 66 + c) * 128 + o];
    WxG0[(size_t)n * 512 + q * 128 + o] = __half2float(__float2half(a));
    return;
  }
  bid -= 2048;
  {  // WxU0: 1024 blocks
    int v = bid * 256 + threadIdx.x;
    int n = v >> 8, q = (v >> 6) & 3, o = v & 63;
    int kk = q >> 1, c = q & 1;
    const float* En = E + n * 16;
    float a = 0.f;
#pragma unroll
    for (int d = 0; d < 16; ++d)
      a += En[d] * uw0[(((size_t)d * 2 + kk) * 66 + c) * 64 + o];
    WxU0[(size_t)n * 256 + q * 64 + o] = __half2float(__float2half(a));
  }
}

// ---------------- Wt via MFMA -> chunk-major pre-swizzled layout, contiguous writes -------
__global__ __launch_bounds__(256) void make_wt_mfma_kernel(
    const __half* __restrict__ E16g, const __half* __restrict__ poolT16g,
    __half* __restrict__ WtG0, __half* __restrict__ WtU0,
    __half* __restrict__ WtG1, __half* __restrict__ WtU1) {
  __shared__ __align__(16) _Float16 Es[64][40];
  __shared__ __align__(16) _Float16 wbuf[64][264];
  const _Float16* E16 = (const _Float16*)E16g;
  const _Float16* pT = (const _Float16*)poolT16g;
  int bx = blockIdx.x;
  __half* Wt; int O, KIP, segbase, kc, og;
  if (bx < 64)       { Wt = WtG0; O = 128; KIP = 128; segbase = 0;     kc = bx & 3;  og = bx >> 2; }
  else if (bx < 96)  { int b = bx - 64;  Wt = WtU0; O = 64;  KIP = 128; segbase = 16384; kc = b & 3; og = b >> 2; }
  else if (bx < 224) { int b = bx - 96;  Wt = WtG1; O = 128; KIP = 256; segbase = 24576; kc = b & 7; og = b >> 3; }
  else               { int b = bx - 224; Wt = WtU1; O = 64;  KIP = 256; segbase = 57344; kc = b & 7; og = b >> 3; }
  int o0 = og * 8;
  int n0 = blockIdx.y * 64;
  {
    int r = threadIdx.x >> 2, ch = (threadIdx.x & 3) * 8;
    *(f16x8*)&Es[r][ch] = *(const f16x8*)(E16 + (size_t)(n0 + r) * 32 + ch);
  }
  __syncthreads();
  int wave = threadIdx.x >> 6, lane = threadIdx.x & 63;
  int fm = lane & 15, fg = lane >> 4;
  f16x8 af[4];
#pragma unroll
  for (int i = 0; i < 4; ++i) af[i] = *(const f16x8*)&Es[i * 16 + fm][fg * 8];
  f32x4 acc[4][4] = {};
#pragma unroll
  for (int jt = 0; jt < 4; ++jt) {
    int local = wave * 64 + jt * 16 + fm;       // 0..255
    int oo = local >> 5, kip = local & 31;
    size_t jc = (size_t)segbase + (size_t)(o0 + oo) * KIP + kc * 32 + kip;
    f16x8 bf = *(const f16x8*)(pT + jc * 32 + fg * 8);
#pragma unroll
    for (int i = 0; i < 4; ++i)
      acc[i][jt] = __builtin_amdgcn_mfma_f32_16x16x32_f16(af[i], bf, acc[i][jt], 0, 0, 0);
  }
#pragma unroll
  for (int i = 0; i < 4; ++i)
#pragma unroll
    for (int jt = 0; jt < 4; ++jt)
#pragma unroll
      for (int r = 0; r < 4; ++r)
        wbuf[i * 16 + fg * 4 + r][wave * 64 + jt * 16 + fm] = (_Float16)acc[i][jt][r];
  __syncthreads();
  int NCH = KIP >> 5;            // chunks per node
  int CH = O * 32;               // halves per chunk
  int sbase = (o0 >> 3) * 256;   // this block's half-offset within the chunk
  for (int idx = threadIdx.x; idx < 64 * 32; idx += 256) {
    int nsub = idx >> 5, w = idx & 31;          // w = slot within our 32-slot run
    int oo = w & 7;
    int s = (w >> 3) ^ (w & 3);                 // o0%8==0 so o&3 == w&3
    int pos = oo * 32 + s * 8;                  // local j of this float4's 8 elems
    size_t dst = ((size_t)(n0 + nsub) * NCH + kc) * CH + sbase + (size_t)w * 8;
    *(float4*)(Wt + dst) = *(float4*)&wbuf[nsub][pos];
  }
}

// ---------------- gemm_nt: Y[1024 x Nc] = Ah @ X (64x64 tile) — prelude Axt ----
__global__ __launch_bounds__(256) void gemm_nt_kernel(
    const __half* __restrict__ Ahg, const __half* __restrict__ X0g,
    const __half* __restrict__ X1g, __half* __restrict__ Yg,
    int Nc, int cstride, int split) {
  __shared__ __align__(16) _Float16 As[64][136];
  __shared__ __align__(16) _Float16 Bs[64][144];
  const _Float16* __restrict__ Ah = (const _Float16*)Ahg;
  _Float16* __restrict__ Y = (_Float16*)Yg;
  int tid = threadIdx.x;
  int row0 = blockIdx.y * 64;
  int col0 = blockIdx.x * 64;
  const _Float16* __restrict__ Xsrc =
      (col0 < split) ? (const _Float16*)X0g : (const _Float16*)X1g;
  int colg = (col0 < split) ? col0 : col0 - split;
  int wave = tid >> 6, lane = tid & 63;
  int wm = wave & 1, wn = wave >> 1;
  int fm = lane & 15, fg = lane >> 4;

  int sr = tid >> 2, sc = (tid & 3) * 32;
  const _Float16* pa = Ah + (size_t)(row0 + sr) * 1024 + sc;
  int kq = tid & 31, cg = tid >> 5;
  int kb = 4 * kq;
  const _Float16* pb = Xsrc + (size_t)kb * cstride + colg + cg * 8;
  int chunk = kq >> 1;
  int kin = (kq & 1) * 4;

  f16x8 ra[4], rb[4];
#pragma unroll
  for (int c = 0; c < 4; ++c) ra[c] = *(const f16x8*)(pa + c * 8);
#pragma unroll
  for (int r = 0; r < 4; ++r) rb[r] = *(const f16x8*)(pb + (size_t)r * cstride);

  f32x4 acc[2][2] = {};
  for (int k0 = 0; k0 < 1024; k0 += 128) {
#pragma unroll
    for (int c = 0; c < 4; ++c) *(f16x8*)&As[sr][sc + c * 8] = ra[c];
#pragma unroll
    for (int i = 0; i < 8; ++i) {
      int c = cg * 8 + i;
      f16x4 p;
      p[0] = rb[0][i]; p[1] = rb[1][i]; p[2] = rb[2][i]; p[3] = rb[3][i];
      *(f16x4*)&Bs[c][((chunk ^ (c & 7)) << 3) + kin] = p;
    }
    __syncthreads();
    if (k0 + 128 < 1024) {
#pragma unroll
      for (int c = 0; c < 4; ++c) ra[c] = *(const f16x8*)(pa + k0 + 128 + c * 8);
#pragma unroll
      for (int r = 0; r < 4; ++r)
        rb[r] = *(const f16x8*)(pb + (size_t)(k0 + 128 + r) * cstride);
    }
#pragma unroll
    for (int kc = 0; kc < 4; ++kc) {
      int ck = kc * 4 + fg;
      f16x8 af[2], bf[2];
#pragma unroll
      for (int i = 0; i < 2; ++i)
        af[i] = *(const f16x8*)&As[wm * 32 + i * 16 + fm][kc * 32 + fg * 8];
#pragma unroll
      for (int j = 0; j < 2; ++j) {
        int cl = wn * 32 + j * 16 + fm;
        bf[j] = *(const f16x8*)&Bs[cl][(ck ^ (cl & 7)) << 3];
      }
#pragma unroll
      for (int i = 0; i < 2; ++i)
#pragma unroll
        for (int j = 0; j < 2; ++j)
          acc[i][j] = __builtin_amdgcn_mfma_f32_16x16x32_f16(af[i], bf[j], acc[i][j], 0, 0, 0);
    }
    __syncthreads();
  }
#pragma unroll
  for (int i = 0; i < 2; ++i) {
#pragma unroll
    for (int j = 0; j < 2; ++j) {
      int col = col0 + wn * 32 + j * 16 + fm;
      int rbase = row0 + wm * 32 + i * 16 + fg * 4;
#pragma unroll
      for (int r = 0; r < 4; ++r)
        Y[(size_t)(rbase + r) * Nc + col] = (_Float16)acc[i][j][r];
    }
  }
}

// ---------------- gemm_nt128: Y = Ah @ X, 64(M) x 128(N) tile, K=128/stage ----------------
__global__ __launch_bounds__(256) void gemm_nt128_kernel(
    const __half* __restrict__ Ahg, const __half* __restrict__ X0g,
    const __half* __restrict__ X1g, __half* __restrict__ Yg,
    int Nc, int cstride, int split) {
  __shared__ __align__(16) _Float16 As[64][136];
  __shared__ __align__(16) _Float16 Bs[128][144];
  const _Float16* __restrict__ Ah = (const _Float16*)Ahg;
  _Float16* __restrict__ Y = (_Float16*)Yg;
  int tid = threadIdx.x;
  int row0 = blockIdx.y * 64;
  int col0 = blockIdx.x * 128;
  const _Float16* __restrict__ Xsrc =
      (col0 < split) ? (const _Float16*)X0g : (const _Float16*)X1g;
  int colg = (col0 < split) ? col0 : col0 - split;
  int wave = tid >> 6, lane = tid & 63;
  int fm = lane & 15, fg = lane >> 4;

  int sr = tid >> 2, sc = (tid & 3) * 32;
  const _Float16* pa = Ah + (size_t)(row0 + sr) * 1024 + sc;
  int kq = tid & 31, cg = tid >> 5;
  int kb = 4 * kq;
  const _Float16* pb = Xsrc + (size_t)kb * cstride + colg + cg * 16;
  int chunk = kq >> 1;
  int kin = (kq & 1) * 4;

  f16x8 ra[4], rb[4][2];
#pragma unroll
  for (int c = 0; c < 4; ++c) ra[c] = *(const f16x8*)(pa + c * 8);
#pragma unroll
  for (int r = 0; r < 4; ++r)
#pragma unroll
    for (int h = 0; h < 2; ++h)
      rb[r][h] = *(const f16x8*)(pb + (size_t)r * cstride + h * 8);

  f32x4 acc[4][2] = {};
  for (int k0 = 0; k0 < 1024; k0 += 128) {
#pragma unroll
    for (int c = 0; c < 4; ++c) *(f16x8*)&As[sr][sc + c * 8] = ra[c];
#pragma unroll
    for (int h = 0; h < 2; ++h)
#pragma unroll
      for (int i = 0; i < 8; ++i) {
        int c = cg * 16 + h * 8 + i;
        f16x4 p;
        p[0] = rb[0][h][i]; p[1] = rb[1][h][i]; p[2] = rb[2][h][i]; p[3] = rb[3][h][i];
        *(f16x4*)&Bs[c][((chunk ^ (c & 7)) << 3) + kin] = p;
      }
    __syncthreads();
    if (k0 + 128 < 1024) {
#pragma unroll
      for (int c = 0; c < 4; ++c) ra[c] = *(const f16x8*)(pa + k0 + 128 + c * 8);
#pragma unroll
      for (int r = 0; r < 4; ++r)
#pragma unroll
        for (int h = 0; h < 2; ++h)
          rb[r][h] = *(const f16x8*)(pb + (size_t)(k0 + 128 + r) * cstride + h * 8);
    }
#pragma unroll
    for (int kc = 0; kc < 4; ++kc) {
      int ck = kc * 4 + fg;
      f16x8 af[4], bf[2];
#pragma unroll
      for (int i = 0; i < 4; ++i)
        af[i] = *(const f16x8*)&As[i * 16 + fm][kc * 32 + fg * 8];
#pragma unroll
      for (int j = 0; j < 2; ++j) {
        int cl = wave * 32 + j * 16 + fm;
        bf[j] = *(const f16x8*)&Bs[cl][(ck ^ (cl & 7)) << 3];
      }
#pragma unroll
      for (int i = 0; i < 4; ++i)
#pragma unroll
        for (int j = 0; j < 2; ++j)
          acc[i][j] = __builtin_amdgcn_mfma_f32_16x16x32_f16(af[i], bf[j], acc[i][j], 0, 0, 0);
    }
    __syncthreads();
  }
#pragma unroll
  for (int i = 0; i < 4; ++i) {
#pragma unroll
    for (int j = 0; j < 2; ++j) {
      int col = col0 + wave * 32 + j * 16 + fm;
      int rbase = row0 + i * 16 + fg * 4;
#pragma unroll
      for (int r = 0; r < 4; ++r)
        Y[(size_t)(rbase + r) * Nc + col] = (_Float16)acc[i][j][r];
    }
  }
}

// ---------------- staging-source helpers (128-col layout: [h|Ah] or [zh|Azh]) -------------
__device__ __forceinline__ f16x8 ld_g0(const __half* __restrict__ h16,
                                       const __half* __restrict__ YBD, int n, int idx) {
  int b = idx >> 4, part = (idx >> 3) & 1, ch = idx & 7;
  const _Float16* s = part ? (const _Float16*)YBD + (size_t)n * 4096 + b * 64 + ch * 8
                           : (const _Float16*)h16 + (size_t)n * 2048 + b * 64 + ch * 8;
  return *(const f16x8*)s;
}
__device__ __forceinline__ f16x8 ld_u0(const __half* __restrict__ zh0,
                                       const __half* __restrict__ YCE, int n, int idx) {
  int b = idx >> 4, part = (idx >> 3) & 1, ch = idx & 7;
  const _Float16* s = part ? (const _Float16*)YCE + (size_t)n * 4096 + 2048 + b * 64 + ch * 8
                           : (const _Float16*)zh0 + (size_t)n * 2048 + b * 64 + ch * 8;
  return *(const f16x8*)s;
}

// ---------------- gate0 body: K=128 (4 chunks), x/Ax folded into epilogue ----------------
// Wn = chunk-major base for node n; chunk stride 4096 halves (O=128). Chunks 0,1 pre-issued.
__device__ __forceinline__ void gate0_body(
    _Float16* Xs, float (*xq)[4], _Float16 (*Wb)[4096], int n, int t,
    f16x8 pre0, f16x8 pre1, float2 xv, unsigned axu,
    const _Float16* Wn, const float* __restrict__ Bg, const float* __restrict__ Wxg,
    const float* __restrict__ h32, __half* __restrict__ zh0, __half* __restrict__ r0) {
  constexpr int STRIDE = 136;
  {
    int b0 = t >> 4, p0 = (t >> 3) & 1, c0 = t & 7;
    *(f16x8*)&Xs[b0 * STRIDE + p0 * 64 + c0 * 8] = pre0;
    int idx = t + 256;
    int b1 = idx >> 4, p1 = (idx >> 3) & 1, c1 = idx & 7;
    *(f16x8*)&Xs[b1 * STRIDE + p1 * 64 + c1 * 8] = pre1;
  }
  if (t < 32) {
    __half2 ah = *(__half2*)&axu;
    float2 af2 = __half22float2(ah);
    xq[t][0] = __half2float(__float2half(xv.x));
    xq[t][1] = __half2float(__float2half(xv.y));
    xq[t][2] = af2.x; xq[t][3] = af2.y;
  }
  int wave = t >> 6, lane = t & 63;
  int fm = lane & 15, fg = lane >> 4;
  f32x4 acc[2][2] = {};
#pragma unroll
  for (int kc = 0; kc < 4; ++kc) {
    if (kc == 0) WAIT_VM2_LG;
    else if (kc < 3) WAIT_VM2;
    else WAIT_VM0;
    BARRIER;
    const _Float16* wb = Wb[kc & 1];
    f16x8 af[2], bf[2];
#pragma unroll
    for (int i = 0; i < 2; ++i)
      af[i] = *(const f16x8*)&Xs[(i * 16 + fm) * STRIDE + kc * 32 + fg * 8];
#pragma unroll
    for (int j = 0; j < 2; ++j)
      bf[j] = wrd(wb, wave * 32 + j * 16 + fm, fg);
    WAIT_LG;
    BARRIER;
    if (kc < 2) dma_g128(Wn + (size_t)(kc + 2) * 4096, Wb[kc & 1], t);
    __builtin_amdgcn_s_setprio(1);
#pragma unroll
    for (int i = 0; i < 2; ++i)
#pragma unroll
      for (int j = 0; j < 2; ++j)
        acc[i][j] = __builtin_amdgcn_mfma_f32_16x16x32_f16(af[i], bf[j], acc[i][j], 0, 0, 0);
    __builtin_amdgcn_s_setprio(0);
  }
  const float* Bn = Bg + n * 128;
  const float* Wx = Wxg + (size_t)n * 512;
#pragma unroll
  for (int j = 0; j < 2; ++j) {
    int o = wave * 32 + j * 16 + fm;
    float bias = Bn[o];
    float w0 = Wx[o], w1 = Wx[128 + o], w2 = Wx[256 + o], w3 = Wx[384 + o];
#pragma unroll
    for (int i = 0; i < 2; ++i)
#pragma unroll
      for (int r = 0; r < 4; ++r) {
        int b = i * 16 + fg * 4 + r;
        float px = acc[i][j][r] + bias +
                   w0 * xq[b][0] + w1 * xq[b][1] + w2 * xq[b][2] + w3 * xq[b][3];
        float s = 1.f / (1.f + __expf(-px));
        size_t base = (size_t)n * 2048 + b * 64;
        if (o < 64) zh0[base + o] = __float2half(s * h32[base + o]);
        else        r0[base + o - 64] = __float2half(s);
      }
  }
}

// ---------------- upd0 body: K=128 (4 chunks), chunk stride 2048 (O=64) ----------
__device__ __forceinline__ void upd0_body(
    _Float16* Xs, float (*xq)[4], _Float16 (*Wb)[2048], int n, int t,
    f16x8 pre0, f16x8 pre1, float2 xv, unsigned axu,
    const _Float16* Wn, const float* __restrict__ Bu, const float* __restrict__ Wxu,
    const __half* __restrict__ r0, float* __restrict__ h32, __half* __restrict__ h16) {
  constexpr int STRIDE = 136;
  {
    int b0 = t >> 4, p0 = (t >> 3) & 1, c0 = t & 7;
    *(f16x8*)&Xs[b0 * STRIDE + p0 * 64 + c0 * 8] = pre0;
    int idx = t + 256;
    int b1 = idx >> 4, p1 = (idx >> 3) & 1, c1 = idx & 7;
    *(f16x8*)&Xs[b1 * STRIDE + p1 * 64 + c1 * 8] = pre1;
  }
  if (t < 32) {
    __half2 ah = *(__half2*)&axu;
    float2 af2 = __half22float2(ah);
    xq[t][0] = __half2float(__float2half(xv.x));
    xq[t][1] = __half2float(__float2half(xv.y));
    xq[t][2] = af2.x; xq[t][3] = af2.y;
  }
  int wave = t >> 6, lane = t & 63;
  int fm = lane & 15, fg = lane >> 4;
  f32x4 acc[2] = {};
#pragma unroll
  for (int kc = 0; kc < 4; ++kc) {
    if (kc == 0) WAIT_VM1_LG;
    else if (kc < 3) WAIT_VM1;
    else WAIT_VM0;
    BARRIER;
    const _Float16* wb = Wb[kc & 1];
    f16x8 bf = wrd(wb, wave * 16 + fm, fg);
    f16x8 af0 = *(const f16x8*)&Xs[(0 * 16 + fm) * STRIDE + kc * 32 + fg * 8];
    f16x8 af1 = *(const f16x8*)&Xs[(1 * 16 + fm) * STRIDE + kc * 32 + fg * 8];
    WAIT_LG;
    BARRIER;
    if (kc < 2) dma_g64(Wn + (size_t)(kc + 2) * 2048, Wb[kc & 1], t);
    __builtin_amdgcn_s_setprio(1);
    acc[0] = __builtin_amdgcn_mfma_f32_16x16x32_f16(af0, bf, acc[0], 0, 0, 0);
    acc[1] = __builtin_amdgcn_mfma_f32_16x16x32_f16(af1, bf, acc[1], 0, 0, 0);
    __builtin_amdgcn_s_setprio(0);
  }
  int o = wave * 16 + fm;
  float bias = Bu[n * 64 + o];
  const float* Wx = Wxu + (size_t)n * 256;
  float w0 = Wx[o], w1 = Wx[64 + o], w2 = Wx[128 + o], w3 = Wx[192 + o];
#pragma unroll
  for (int i = 0; i < 2; ++i)
#pragma unroll
    for (int r = 0; r < 4; ++r) {
      int b = i * 16 + fg * 4 + r;
      float x = acc[i][r] + bias +
                w0 * xq[b][0] + w1 * xq[b][1] + w2 * xq[b][2] + w3 * xq[b][3];
      x = fminf(fmaxf(x, -15.f), 15.f);
      float e = __expf(2.f * x);
      float hc = (e - 1.f) / (e + 1.f);
      size_t base = (size_t)n * 2048 + b * 64;
      float rr = __half2float(r0[base + o]);
      float hnew = rr * h32[base + o] + (1.f - rr) * hc;
      h32[base + o] = hnew;
      h16[base + o] = __float2half(hnew);
    }
}

// ---------------- standalone gate0 / upd0 (prologue) ----------------
__global__ __launch_bounds__(256) void gate0_kernel(
    const __half* __restrict__ h16, const __half* __restrict__ YBD,
    const float* __restrict__ src, const __half* __restrict__ Axt, int tstep,
    const __half* __restrict__ Wtg, const float* __restrict__ Bg,
    const float* __restrict__ Wxg,
    const float* __restrict__ h32, __half* __restrict__ zh0, __half* __restrict__ r0) {
  __shared__ __align__(16) _Float16 Xs[32 * 136];
  __shared__ __align__(16) _Float16 Wb[2][4096];
  __shared__ float xq[32][4];
  int n = blockIdx.x, t = threadIdx.x;
  const _Float16* Wn = (const _Float16*)Wtg + (size_t)n * 16384;  // 4 chunks * 4096
  f16x8 p0 = ld_g0(h16, YBD, n, t);
  f16x8 p1 = ld_g0(h16, YBD, n, t + 256);
  float2 xv = {}; unsigned ax = 0;
  if (t < 32) {
    xv = *(const float2*)(src + ((size_t)(t * 12 + tstep) * 1024 + n) * 2);
    ax = *(const unsigned*)((const _Float16*)Axt + (size_t)n * 768 + tstep * 64 + t * 2);
  }
  dma_g128(Wn, Wb[0], t);
  dma_g128(Wn + 4096, Wb[1], t);
  gate0_body(Xs, xq, Wb, n, t, p0, p1, xv, ax, Wn, Bg, Wxg, h32, zh0, r0);
}

__global__ __launch_bounds__(256) void upd0_kernel(
    const __half* __restrict__ zh0, const __half* __restrict__ YCE,
    const float* __restrict__ src, const __half* __restrict__ Axt, int tstep,
    const __half* __restrict__ Wtg, const float* __restrict__ Bu,
    const float* __restrict__ Wxu,
    const __half* __restrict__ r0, float* __restrict__ h32, __half* __restrict__ h16) {
  __shared__ __align__(16) _Float16 Xs[32 * 136];
  __shared__ __align__(16) _Float16 Wb[2][2048];
  __shared__ float xq[32][4];
  int n = blockIdx.x, t = threadIdx.x;
  const _Float16* Wn = (const _Float16*)Wtg + (size_t)n * 8192;  // 4 chunks * 2048
  f16x8 p0 = ld_u0(zh0, YCE, n, t);
  f16x8 p1 = ld_u0(zh0, YCE, n, t + 256);
  float2 xv = {}; unsigned ax = 0;
  if (t < 32) {
    xv = *(const float2*)(src + ((size_t)(t * 12 + tstep) * 1024 + n) * 2);
    ax = *(const unsigned*)((const _Float16*)Axt + (size_t)n * 768 + tstep * 64 + t * 2);
  }
  dma_g64(Wn, Wb[0], t);
  dma_g64(Wn + 2048, Wb[1], t);
  upd0_body(Xs, xq, Wb, n, t, p0, p1, xv, ax, Wn, Bu, Wxu, r0, h32, h16);
}

// ---------------- F1: gate1(t) + gate0(t+1) ----------------
__global__ __launch_bounds__(256) void gate1_gate0_kernel(
    const __half* __restrict__ h1_16, const __half* __restrict__ h2_16,
    const __half* __restrict__ YBD,
    const __half* __restrict__ WtG1, const float* __restrict__ Bg1,
    const float* __restrict__ h2_32, __half* __restrict__ zh1, __half* __restrict__ r1,
    const float* __restrict__ src, const __half* __restrict__ Axt, int tnext,
    const __half* __restrict__ WtG0, const float* __restrict__ Bg0,
    const float* __restrict__ WxG0,
    const float* __restrict__ h1_32, __half* __restrict__ zh0, __half* __restrict__ r0,
    int do_gate0) {
  constexpr int STRIDE = 264;
  __shared__ __align__(16) _Float16 Xs[32 * STRIDE];
  __shared__ __align__(16) _Float16 Wb[2][4096];
  __shared__ float xq[32][4];
  int n = blockIdx.x;
  int t = threadIdx.x;
  const _Float16* Wn1 = (const _Float16*)WtG1 + (size_t)n * 32768;  // 8 chunks * 4096
  const _Float16* Wn0 = (const _Float16*)WtG0 + (size_t)n * 16384;  // 4 chunks * 4096
  // phase-1 staging loads
  f16x8 s1[4];
#pragma unroll
  for (int u = 0; u < 4; ++u) {
    int idx = t + u * 256;
    int b = idx >> 5, q = idx & 31;
    const _Float16* s;
    if (q < 8)       s = (const _Float16*)h1_16 + (size_t)n * 2048 + b * 64 + q * 8;
    else if (q < 16) s = (const _Float16*)h2_16 + (size_t)n * 2048 + b * 64 + (q - 8) * 8;
    else if (q < 24) s = (const _Float16*)YBD + (size_t)n * 4096 + b * 64 + (q - 16) * 8;
    else             s = (const _Float16*)YBD + (size_t)n * 4096 + 2048 + b * 64 + (q - 24) * 8;
    s1[u] = *(const f16x8*)s;
  }
  // phase-2 prefetch (T14)
  f16x8 g0p0 = {}, g0p1 = {}; float2 g0xv = {}; unsigned g0ax = 0;
  if (do_gate0) {
    g0p0 = ld_g0(h1_16, YBD, n, t);
    g0p1 = ld_g0(h1_16, YBD, n, t + 256);
    if (t < 32) {
      g0xv = *(const float2*)(src + ((size_t)(t * 12 + tnext) * 1024 + n) * 2);
      g0ax = *(const unsigned*)((const _Float16*)Axt + (size_t)n * 768 + tnext * 64 + t * 2);
    }
  }
  // phase-1 weight chunks 0,1
  dma_g128(Wn1, Wb[0], t);
  dma_g128(Wn1 + 4096, Wb[1], t);
#pragma unroll
  for (int u = 0; u < 4; ++u) {
    int idx = t + u * 256;
    int b = idx >> 5, q = idx & 31;
    *(f16x8*)&Xs[b * STRIDE + q * 8] = s1[u];
  }
  int wave = t >> 6, lane = t & 63;
  int fm = lane & 15, fg = lane >> 4;
  {
    f32x4 acc[2][2] = {};
#pragma unroll
    for (int kc = 0; kc < 8; ++kc) {
      if (kc == 0) WAIT_VM2_LG;
      else if (kc < 7) WAIT_VM2;
      else { if (do_gate0) WAIT_VM2; else WAIT_VM0; }
      BARRIER;
      const _Float16* wb = Wb[kc & 1];
      f16x8 af[2], bf[2];
#pragma unroll
      for (int i = 0; i < 2; ++i)
        af[i] = *(const f16x8*)&Xs[(i * 16 + fm) * STRIDE + kc * 32 + fg * 8];
#pragma unroll
      for (int j = 0; j < 2; ++j)
        bf[j] = wrd(wb, wave * 32 + j * 16 + fm, fg);
      WAIT_LG;
      BARRIER;
      if (kc < 6) dma_g128(Wn1 + (size_t)(kc + 2) * 4096, Wb[kc & 1], t);
      else if (do_gate0) dma_g128(Wn0 + (size_t)(kc - 6) * 4096, Wb[kc & 1], t);
      __builtin_amdgcn_s_setprio(1);
#pragma unroll
      for (int i = 0; i < 2; ++i)
#pragma unroll
        for (int j = 0; j < 2; ++j)
          acc[i][j] = __builtin_amdgcn_mfma_f32_16x16x32_f16(af[i], bf[j], acc[i][j], 0, 0, 0);
      __builtin_amdgcn_s_setprio(0);
    }
    const float* Bn = Bg1 + n * 128;
#pragma unroll
    for (int j = 0; j < 2; ++j) {
      int o = wave * 32 + j * 16 + fm;
      float bias = Bn[o];
#pragma unroll
      for (int i = 0; i < 2; ++i)
#pragma unroll
        for (int r = 0; r < 4; ++r) {
          int b = i * 16 + fg * 4 + r;
          float s = 1.f / (1.f + __expf(-(acc[i][j][r] + bias)));
          size_t base = (size_t)n * 2048 + b * 64;
          if (o < 64) zh1[base + o] = __float2half(s * h2_32[base + o]);
          else        r1[base + o - 64] = __float2half(s);
        }
    }
  }
  if (!do_gate0) return;
  gate0_body(Xs, xq, Wb, n, t, g0p0, g0p1, g0xv, g0ax, Wn0, Bg0, WxG0, h1_32, zh0, r0);
}

// ---------------- F2: upd1(t) + upd0(t+1) ----------------
__global__ __launch_bounds__(256) void upd1_upd0_kernel(
    const __half* __restrict__ h1_16, const __half* __restrict__ zh1,
    const __half* __restrict__ YBD, const __half* __restrict__ YCE,
    const __half* __restrict__ WtU1, const float* __restrict__ Bu1,
    const __half* __restrict__ r1, float* __restrict__ h2_32, __half* __restrict__ h2_16,
    const __half* __restrict__ zh0,
    const float* __restrict__ src, const __half* __restrict__ Axt, int tnext,
    const __half* __restrict__ WtU0, const float* __restrict__ Bu0,
    const float* __restrict__ WxU0,
    const __half* __restrict__ r0, float* __restrict__ h1_32, __half* __restrict__ h1_16w,
    int do_upd0) {
  constexpr int STRIDE = 264;
  __shared__ __align__(16) _Float16 Xs[32 * STRIDE];
  __shared__ __align__(16) _Float16 Wb[2][2048];
  __shared__ float xq[32][4];
  int n = blockIdx.x;
  int t = threadIdx.x;
  const _Float16* Wn1 = (const _Float16*)WtU1 + (size_t)n * 16384;  // 8 chunks * 2048
  const _Float16* Wn0 = (const _Float16*)WtU0 + (size_t)n * 8192;   // 4 chunks * 2048
  // phase-1 staging loads
  f16x8 s1[4];
#pragma unroll
  for (int u = 0; u < 4; ++u) {
    int idx = t + u * 256;
    int b = idx >> 5, q = idx & 31;
    const _Float16* s;
    if (q < 8)       s = (const _Float16*)h1_16 + (size_t)n * 2048 + b * 64 + q * 8;
    else if (q < 16) s = (const _Float16*)zh1 + (size_t)n * 2048 + b * 64 + (q - 8) * 8;
    else if (q < 24) s = (const _Float16*)YBD + (size_t)n * 4096 + b * 64 + (q - 16) * 8;
    else             s = (const _Float16*)YCE + (size_t)n * 4096 + b * 64 + (q - 24) * 8;
    s1[u] = *(const f16x8*)s;
  }
  // phase-2 prefetch (T14)
  f16x8 u0p0 = {}, u0p1 = {}; float2 u0xv = {}; unsigned u0ax = 0;
  if (do_upd0) {
    u0p0 = ld_u0(zh0, YCE, n, t);
    u0p1 = ld_u0(zh0, YCE, n, t + 256);
    if (t < 32) {
      u0xv = *(const float2*)(src + ((size_t)(t * 12 + tnext) * 1024 + n) * 2);
      u0ax = *(const unsigned*)((const _Float16*)Axt + (size_t)n * 768 + tnext * 64 + t * 2);
    }
  }
  // phase-1 weight chunks 0,1
  dma_g64(Wn1, Wb[0], t);
  dma_g64(Wn1 + 2048, Wb[1], t);
#pragma unroll
  for (int u = 0; u < 4; ++u) {
    int idx = t + u * 256;
    int b = idx >> 5, q = idx & 31;
    *(f16x8*)&Xs[b * STRIDE + q * 8] = s1[u];
  }
  int wave = t >> 6, lane = t & 63;
  int fm = lane & 15, fg = lane >> 4;
  {
    f32x4 acc[2] = {};
#pragma unroll
    for (int kc = 0; kc < 8; ++kc) {
      if (kc == 0) WAIT_VM1_LG;
      else if (kc < 7) WAIT_VM1;
      else { if (do_upd0) WAIT_VM1; else WAIT_VM0; }
      BARRIER;
      const _Float16* wb = Wb[kc & 1];
      f16x8 bf = wrd(wb, wave * 16 + fm, fg);
      f16x8 af0 = *(const f16x8*)&Xs[(0 * 16 + fm) * STRIDE + kc * 32 + fg * 8];
      f16x8 af1 = *(const f16x8*)&Xs[(1 * 16 + fm) * STRIDE + kc * 32 + fg * 8];
      WAIT_LG;
      BARRIER;
      if (kc < 6) dma_g64(Wn1 + (size_t)(kc + 2) * 2048, Wb[kc & 1], t);
      else if (do_upd0) dma_g64(Wn0 + (size_t)(kc - 6) * 2048, Wb[kc & 1], t);
      __builtin_amdgcn_s_setprio(1);
      acc[0] = __builtin_amdgcn_mfma_f32_16x16x32_f16(af0, bf, acc[0], 0, 0, 0);
      acc[1] = __builtin_amdgcn_mfma_f32_16x16x32_f16(af1, bf, acc[1], 0, 0, 0);
      __builtin_amdgcn_s_setprio(0);
    }
    int o = wave * 16 + fm;
    float bias = Bu1[n * 64 + o];
#pragma unroll
    for (int i = 0; i < 2; ++i)
#pragma unroll
      for (int r = 0; r < 4; ++r) {
        int b = i * 16 + fg * 4 + r;
        float x = acc[i][r] + bias;
        x = fminf(fmaxf(x, -15.f), 15.f);
        float e = __expf(2.f * x);
        float hc = (e - 1.f) / (e + 1.f);
        size_t base = (size_t)n * 2048 + b * 64;
        float rr = __half2float(r1[base + o]);
        float hnew = rr * h2_32[base + o] + (1.f - rr) * hc;
        h2_32[base + o] = hnew;
        h2_16[base + o] = __float2half(hnew);
      }
  }
  if (!do_upd0) return;
  upd0_body(Xs, xq, Wb, n, t, u0p0, u0p1, u0xv, u0ax, Wn0, Bu0, WxU0, r0, h1_32, h1_16w);
}

// ---------------- out[b,o,n] = h2[n,b,:] . conv_w[o,:] + conv_b[o] ----------------
__global__ void final_conv_kernel(const float* __restrict__ h2, const float* __restrict__ cw,
                                  const float* __restrict__ cb, float* __restrict__ out) {
  int tid = blockIdx.x * 256 + threadIdx.x;
  if (tid >= 32 * 1024) return;
  int n = tid & 1023, b = tid >> 10;
  const float* hp = h2 + ((size_t)n * 32 + b) * 64;
  float hv[64];
#pragma unroll
  for (int i = 0; i < 64; ++i) hv[i] = hp[i];
#pragma unroll
  for (int o = 0; o < 12; ++o) {
    float acc = cb[o];
#pragma unroll
    for (int i = 0; i < 64; ++i) acc += hv[i] * cw[o * 64 + i];
    out[((size_t)b * 12 + o) * 1024 + n] = acc;
  }
}

extern "C" void kernel_launch(void* const* d_in, const int* in_sizes, int n_in,
                              void* d_out, int out_size, void* d_ws, size_t ws_size,
                              hipStream_t stream) {
  const float* src = (const float*)d_in[0];
  const float* E   = (const float*)d_in[1];
  const float* gw0 = (const float*)d_in[2];
  const float* gb0 = (const float*)d_in[3];
  const float* uw0 = (const float*)d_in[4];
  const float* ub0 = (const float*)d_in[5];
  const float* gw1 = (const float*)d_in[6];
  const float* gb1 = (const float*)d_in[7];
  const float* uw1 = (const float*)d_in[8];
  const float* ub1 = (const float*)d_in[9];
  const float* cw  = (const float*)d_in[10];
  const float* cb  = (const float*)d_in[11];
  float* out = (float*)d_out;
  (void)in_sizes; (void)n_in; (void)out_size; (void)ws_size;

  char* base = (char*)d_ws;
  size_t off = 0;
  auto alloc = [&](size_t bytes) -> void* {
    void* p = base + off; off += (bytes + 511) & ~(size_t)511; return p;
  };
  __half* Ah   = (__half*)alloc((size_t)1024 * 1024 * 2);           //   2.1 MB
  __half* WtG0 = (__half*)alloc((size_t)1024 * 128 * 128 * 2);      //  33.6 MB (K=128)
  __half* WtU0 = (__half*)alloc((size_t)1024 * 64 * 128 * 2);       //  16.8 MB (K=128)
  __half* WtG1 = (__half*)alloc((size_t)1024 * 128 * 256 * 2);      //  67.1 MB
  __half* WtU1 = (__half*)alloc((size_t)1024 * 64 * 256 * 2);       //  33.6 MB
  float*  Bg0  = (float*) alloc((size_t)1024 * 128 * 4);
  float*  Bu0  = (float*) alloc((size_t)1024 * 64 * 4);
  float*  Bg1  = (float*) alloc((size_t)1024 * 128 * 4);
  float*  Bu1  = (float*) alloc((size_t)1024 * 64 * 4);
  float*  WxG0 = (float*) alloc((size_t)1024 * 512 * 4);            //   2.1 MB
  float*  WxU0 = (float*) alloc((size_t)1024 * 256 * 4);            //   1.0 MB
  // zero-init region (contiguous): h1_32, h2_32, h1_16, h2_16, YBD  (8388608 floats)
  float*  h1_32 = (float*)alloc((size_t)1024 * 2048 * 4);           //   8.4 MB
  float*  h2_32 = (float*)alloc((size_t)1024 * 2048 * 4);           //   8.4 MB
  __half* h1_16 = (__half*)alloc((size_t)1024 * 2048 * 2);          //   4.2 MB
  __half* h2_16 = (__half*)alloc((size_t)1024 * 2048 * 2);          //   4.2 MB
  __half* YBD  = (__half*)alloc((size_t)1024 * 4096 * 2);           //   8.4 MB [A@h1 | A@h2]
  __half* YCE  = (__half*)alloc((size_t)1024 * 4096 * 2);           //   8.4 MB [A@zh1 | A@zh0]
  __half* zh0  = (__half*)alloc((size_t)1024 * 2048 * 2);           //   4.2 MB
  __half* zh1  = (__half*)alloc((size_t)1024 * 2048 * 2);           //   4.2 MB
  __half* Axt  = (__half*)alloc((size_t)1024 * 768 * 2);            //   1.5 MB (A@x all t)
  __half* r1   = (__half*)alloc((size_t)1024 * 2048 * 2);           //   4.2 MB
  __half* r0   = (__half*)alloc((size_t)1024 * 2048 * 2);           //   4.2 MB
  __half* poolT16 = (__half*)alloc((size_t)73728 * 32 * 2);         //   4.7 MB
  __half* E16  = (__half*)alloc((size_t)1024 * 32 * 2);             //  64 KB
  __half* x16  = (__half*)alloc((size_t)1024 * 768 * 2);            //   1.5 MB
  // total ~222 MB

  // ---- prelude (5 dispatches) ----
  compute_A_kernel<<<1024, 256, 0, stream>>>(E, Ah);
  prelude_misc_kernel<<<13312, 256, 0, stream>>>(E, E16, gb0, ub0, gb1, ub1,
                                                 Bg0, Bu0, Bg1, Bu1,
                                                 src, x16, gw0, uw0, WxG0, WxU0,
                                                 (float4*)h1_32);
  pool_t16_kernel<<<768, 256, 0, stream>>>(gw0, uw0, gw1, uw1, poolT16);
  make_wt_mfma_kernel<<<dim3(288, 16), 256, 0, stream>>>(E16, poolT16, WtG0, WtU0, WtG1, WtU1);
  gemm_nt_kernel<<<dim3(12, 16), 256, 0, stream>>>(Ah, (__half*)x16, (__half*)x16, Axt,
                                                   768, 768, 768);

  // ---- prologue: layer-0 step 0 ----
  gate0_kernel<<<1024, 256, 0, stream>>>(h1_16, YBD, src, Axt, 0, WtG0, Bg0, WxG0,
                                         h1_32, zh0, r0);
  gemm_nt128_kernel<<<dim3(16, 16), 256, 0, stream>>>(Ah, zh0, zh0, YCE + 2048,
                                                      4096, 2048, 2048);  // YE = A@zh0(0)
  upd0_kernel<<<1024, 256, 0, stream>>>(zh0, YCE, src, Axt, 0, WtU0, Bu0, WxU0,
                                        r0, h1_32, h1_16);

  // ---- 12 pipelined iterations (4 dispatches each) ----
  for (int t = 0; t < 12; ++t) {
    int more = (t < 11) ? 1 : 0;
    gemm_nt128_kernel<<<dim3(32, 16), 256, 0, stream>>>(Ah, h1_16, h2_16, YBD,
                                                        4096, 2048, 2048);   // G1
    gate1_gate0_kernel<<<1024, 256, 0, stream>>>(h1_16, h2_16, YBD, WtG1, Bg1, h2_32, zh1, r1,
                                                 src, Axt, t + 1, WtG0, Bg0, WxG0,
                                                 h1_32, zh0, r0, more);       // F1
    gemm_nt128_kernel<<<dim3(32, 16), 256, 0, stream>>>(Ah, zh1, zh0, YCE,
                                                        4096, 2048, 2048);   // G2
    upd1_upd0_kernel<<<1024, 256, 0, stream>>>(h1_16, zh1, YBD, YCE, WtU1, Bu1, r1,
                                               h2_32, h2_16, zh0, src, Axt, t + 1,
                                               WtU0, Bu0, WxU0, r0, h1_32, h1_16, more);  // F2
  }

  final_conv_kernel<<<(32 * 1024 + 255) / 256, 256, 0, stream>>>(h2_32, cw, cb, out);
}

// Round 8
// 1240.635 us; speedup vs baseline: 1.1785x; 1.0671x over previous
//
#include <hip/hip_runtime.h>
#include <hip/hip_fp16.h>

// AGCRN: B=32 T=12 N=1024 C=2 D=16 H=64 K=2 OUT=12
// Node-major activations [n][(b,f)], fp16 on GEMM paths; h fp32 master + fp16 mirror.
// Cross-layer software pipeline: per loop iter t handles layer1(t) + layer0(t+1):
//   G1: A@[h1(t)|h2(t-1)] -> YBD     F1: gate1(t)+gate0(t+1)
//   G2: A@[zh1(t)|zh0(t+1)] -> YCE   F2: upd1(t)+upd0(t+1)
// Round 17: GATE weights (WtG0/WtG1) stored fp8 e4m3 (OCP) — halves the F1 weight stream
// (100->50 MB/iter). Reader converts fp8->f16 in-register (exact); activations stay fp16;
// update/tanh weights stay fp16. DMA chunks 4KB, vmcnt ladder re-derived (VM1 steady).

typedef _Float16 f16x8 __attribute__((ext_vector_type(8)));
typedef _Float16 f16x4 __attribute__((ext_vector_type(4)));
typedef float f32x4 __attribute__((ext_vector_type(4)));
typedef float f32x2 __attribute__((ext_vector_type(2)));

#define WAIT_VM0 asm volatile("s_waitcnt vmcnt(0)" ::: "memory")
#define WAIT_VM1 asm volatile("s_waitcnt vmcnt(1)" ::: "memory")
#define WAIT_VM1_LG asm volatile("s_waitcnt vmcnt(1) lgkmcnt(0)" ::: "memory")
#define WAIT_LG asm volatile("s_waitcnt lgkmcnt(0)" ::: "memory")
#define BARRIER do { __builtin_amdgcn_s_barrier(); asm volatile("" ::: "memory"); } while (0)

// ---- weight-chunk DMA. Chunk kc of node n stored contiguously in LDS flat-slot order:
// flat = (o&7) | ((s^(o&3))<<3) | ((o>>3)<<5). Gate chunks: fp8, 8B/slot, 4KB (O=128).
// Upd chunks: fp16, 16B/slot, 4KB (O=64).
__device__ __forceinline__ void gload_lds16(const void* g, void* l) {
  __builtin_amdgcn_global_load_lds(
      (const __attribute__((address_space(1))) void*)g,
      (__attribute__((address_space(3))) void*)l, 16, 0, 0);
}

// 4KB chunk: 256 threads x 16B, fully linear.
__device__ __forceinline__ void dma_b4k(const unsigned char* Wc, unsigned char* buf, int tid) {
  gload_lds16(Wc + (size_t)tid * 16, buf + (size_t)tid * 16);
}

__device__ __forceinline__ void dma_g64(const _Float16* Wc, _Float16* buf, int tid) {
  int wave = tid >> 6;
  gload_lds16(Wc + (size_t)tid * 8, buf + (size_t)(wave * 64) * 8);
}

// fp16 upd-weight read (16B/slot)
__device__ __forceinline__ f16x8 wrd(const _Float16* buf, int o, int s) {
  int flat = (o & 7) | (((s ^ (o & 3)) & 3) << 3) | ((o >> 3) << 5);
  return *(const f16x8*)(buf + flat * 8);
}

// fp8 gate-weight read (8B/slot) + exact fp8->f16 convert
__device__ __forceinline__ f16x8 wrd8(const unsigned char* buf, int o, int s) {
  int flat = (o & 7) | (((s ^ (o & 3)) & 3) << 3) | ((o >> 3) << 5);
  const unsigned* p = (const unsigned*)(buf + flat * 8);
  unsigned lo = p[0], hi = p[1];
  f32x2 a0 = __builtin_amdgcn_cvt_pk_f32_fp8(lo, 0);
  f32x2 a1 = __builtin_amdgcn_cvt_pk_f32_fp8(lo, 1);
  f32x2 a2 = __builtin_amdgcn_cvt_pk_f32_fp8(hi, 0);
  f32x2 a3 = __builtin_amdgcn_cvt_pk_f32_fp8(hi, 1);
  f16x8 r;
  r[0] = (_Float16)a0[0]; r[1] = (_Float16)a0[1];
  r[2] = (_Float16)a1[0]; r[3] = (_Float16)a1[1];
  r[4] = (_Float16)a2[0]; r[5] = (_Float16)a2[1];
  r[6] = (_Float16)a3[0]; r[7] = (_Float16)a3[1];
  return r;
}

// ---------------- A = softmax(relu(E E^T)) -> fp16 ----------------
__global__ __launch_bounds__(256) void compute_A_kernel(const float* __restrict__ E,
                                                        __half* __restrict__ Ah) {
  int n = blockIdx.x;
  int tid = threadIdx.x;
  __shared__ float red[256];
  float en[16];
#pragma unroll
  for (int d = 0; d < 16; ++d) en[d] = E[n * 16 + d];
  float v[4];
#pragma unroll
  for (int q = 0; q < 4; ++q) {
    int m = tid + q * 256;
    const float* Em = E + m * 16;
    float dot = 0.f;
#pragma unroll
    for (int d = 0; d < 16; ++d) dot += en[d] * Em[d];
    v[q] = fmaxf(dot, 0.f);
  }
  float mx = fmaxf(fmaxf(v[0], v[1]), fmaxf(v[2], v[3]));
  red[tid] = mx; __syncthreads();
  for (int s = 128; s > 0; s >>= 1) { if (tid < s) red[tid] = fmaxf(red[tid], red[tid + s]); __syncthreads(); }
  mx = red[0];
  __syncthreads();
  float e[4], sum = 0.f;
#pragma unroll
  for (int q = 0; q < 4; ++q) { e[q] = expf(v[q] - mx); sum += e[q]; }
  red[tid] = sum; __syncthreads();
  for (int s = 128; s > 0; s >>= 1) { if (tid < s) red[tid] += red[tid + s]; __syncthreads(); }
  float inv = 1.f / red[0];
#pragma unroll
  for (int q = 0; q < 4; ++q) Ah[(size_t)n * 1024 + tid + q * 256] = __float2half(e[q] * inv);
}

// ---------------- poolT16[j][d]: K-contiguous fp16 pool (h-columns only for layer 0) ------
__global__ __launch_bounds__(256) void pool_t16_kernel(const float* __restrict__ gw0,
                                                       const float* __restrict__ uw0,
                                                       const float* __restrict__ gw1,
                                                       const float* __restrict__ uw1,
                                                       __half* __restrict__ poolT16) {
  int rg = blockIdx.x;  // 0..767
  const float* pool; int F, O, TK; size_t jb; int kk, jj, i;
  if (rg < 128)      { pool = gw0; F = 66;  O = 128; TK = 64;  jb = 0;     kk = rg >> 6; jj = rg & 63; i = jj + 2; }
  else if (rg < 256) { int r = rg - 128; pool = uw0; F = 66;  O = 64;  TK = 64;  jb = 16384; kk = r >> 6; jj = r & 63;  i = jj + 2; }
  else if (rg < 512) { int r = rg - 256; pool = gw1; F = 128; O = 128; TK = 128; jb = 24576; kk = r >> 7; jj = r & 127; i = jj; }
  else               { int r = rg - 512; pool = uw1; F = 128; O = 64;  TK = 128; jb = 57344; kk = r >> 7; jj = r & 127; i = jj; }
  int o = threadIdx.x;
  if (o >= O) return;
  f16x8 a, b, zz = {};
#pragma unroll
  for (int d = 0; d < 8; ++d)
    a[d] = (_Float16)pool[(((size_t)d * 2 + kk) * F + i) * O + o];
#pragma unroll
  for (int d = 8; d < 16; ++d)
    b[d - 8] = (_Float16)pool[(((size_t)d * 2 + kk) * F + i) * O + o];
  size_t j = jb + (size_t)o * (2 * TK) + (size_t)kk * TK + jj;
  _Float16* outp = (_Float16*)poolT16 + j * 32;
  *(f16x8*)outp = a;
  *(f16x8*)(outp + 8) = b;
  *(f16x8*)(outp + 16) = zz;
  *(f16x8*)(outp + 24) = zz;
}

// ---------------- fused prelude: zero + x16 + biases + E16 + Wx coefficients ----------------
__global__ __launch_bounds__(256) void prelude_misc_kernel(
    const float* __restrict__ E, __half* __restrict__ E16,
    const float* __restrict__ gb0, const float* __restrict__ ub0,
    const float* __restrict__ gb1, const float* __restrict__ ub1,
    float* __restrict__ Bg0, float* __restrict__ Bu0,
    float* __restrict__ Bg1, float* __restrict__ Bu1,
    const float* __restrict__ src, __half* __restrict__ x16,
    const float* __restrict__ gw0, const float* __restrict__ uw0,
    float* __restrict__ WxG0, float* __restrict__ WxU0,
    float4* __restrict__ zero_p) {
  int bid = blockIdx.x;
  if (bid < 8192) {
    int i = bid * 256 + threadIdx.x;
    zero_p[i] = float4{0.f, 0.f, 0.f, 0.f};
    return;
  }
  bid -= 8192;
  if (bid < 384) {
    int t0 = bid >> 5, b = bid & 31;
    const float* s = src + (size_t)(b * 12 + t0) * 2048;
    __half* dst = x16 + t0 * 64 + b * 2;
    for (int nn = threadIdx.x; nn < 1024; nn += 256) {
      float2 v = *(const float2*)(s + nn * 2);
      *(__half2*)(dst + (size_t)nn * 768) = __floats2half2_rn(v.x, v.y);
    }
    return;
  }
  bid -= 384;
  if (bid < 1536) {
    int tid = bid * 256 + threadIdx.x;
    if (tid >= 1024 * 384) return;
    int n = tid / 384, c = tid - n * 384;
    const float* pool; float* outp; int O, o;
    if (c < 128)      { pool = gb0; outp = Bg0; O = 128; o = c; }
    else if (c < 192) { pool = ub0; outp = Bu0; O = 64;  o = c - 128; }
    else if (c < 320) { pool = gb1; outp = Bg1; O = 128; o = c - 192; }
    else              { pool = ub1; outp = Bu1; O = 64;  o = c - 320; }
    const float* En = E + n * 16;
    float a = 0.f;
#pragma unroll
    for (int d = 0; d < 16; ++d) a += En[d] * pool[d * O + o];
    outp[n * O + o] = a;
    return;
  }
  bid -= 1536;
  if (bid < 128) {
    int t = bid * 256 + threadIdx.x;
    int d = t & 31;
    E16[t] = (d < 16) ? __float2half(E[(t >> 5) * 16 + d]) : __half(0);
    return;
  }
  bid -= 128;
  if (bid < 2048) {  // WxG0[n][kk*2+c][o], fp16-rounded
    int v = bid * 256 + threadIdx.x;
    int n = v >> 9, q = (v >> 7) & 3, o = v & 127;
    int kk = q >> 1, c = q & 1;
    const float* En = E + n * 16;
    float a = 0.f;
#pragma unroll
    for (int d = 0; d < 16; ++d)
      a += En[d] * gw0[(((size_t)d * 2 + kk) * 66 + c) * 128 + o];
    WxG0[(size_t)n * 512 + q * 128 + o] = __half2float(__float2half(a));
    return;
  }
  bid -= 2048;
  {  // WxU0
    int v = bid * 256 + threadIdx.x;
    int n = v >> 8, q = (v >> 6) & 3, o = v & 63;
    int kk = q >> 1, c = q & 1;
    const float* En = E + n * 16;
    float a = 0.f;
#pragma unroll
    for (int d = 0; d < 16; ++d)
      a += En[d] * uw0[(((size_t)d * 2 + kk) * 66 + c) * 64 + o];
    WxU0[(size_t)n * 256 + q * 64 + o] = __half2float(__float2half(a));
  }
}

// ---------------- Wt via MFMA -> chunk-major pre-swizzled; gate segs fp8, upd segs fp16 ----
__global__ __launch_bounds__(256) void make_wt_mfma_kernel(
    const __half* __restrict__ E16g, const __half* __restrict__ poolT16g,
    unsigned char* __restrict__ WtG0, __half* __restrict__ WtU0,
    unsigned char* __restrict__ WtG1, __half* __restrict__ WtU1) {
  __shared__ __align__(16) _Float16 Es[64][40];
  __shared__ __align__(16) _Float16 wbuf[64][264];
  const _Float16* E16 = (const _Float16*)E16g;
  const _Float16* pT = (const _Float16*)poolT16g;
  int bx = blockIdx.x;
  void* Wt; int O, KIP, segbase, kc, og, fp8;
  if (bx < 64)       { Wt = WtG0; O = 128; KIP = 128; segbase = 0;     kc = bx & 3;  og = bx >> 2; fp8 = 1; }
  else if (bx < 96)  { int b = bx - 64;  Wt = WtU0; O = 64;  KIP = 128; segbase = 16384; kc = b & 3; og = b >> 2; fp8 = 0; }
  else if (bx < 224) { int b = bx - 96;  Wt = WtG1; O = 128; KIP = 256; segbase = 24576; kc = b & 7; og = b >> 3; fp8 = 1; }
  else               { int b = bx - 224; Wt = WtU1; O = 64;  KIP = 256; segbase = 57344; kc = b & 7; og = b >> 3; fp8 = 0; }
  int o0 = og * 8;
  int n0 = blockIdx.y * 64;
  {
    int r = threadIdx.x >> 2, ch = (threadIdx.x & 3) * 8;
    *(f16x8*)&Es[r][ch] = *(const f16x8*)(E16 + (size_t)(n0 + r) * 32 + ch);
  }
  __syncthreads();
  int wave = threadIdx.x >> 6, lane = threadIdx.x & 63;
  int fm = lane & 15, fg = lane >> 4;
  f16x8 af[4];
#pragma unroll
  for (int i = 0; i < 4; ++i) af[i] = *(const f16x8*)&Es[i * 16 + fm][fg * 8];
  f32x4 acc[4][4] = {};
#pragma unroll
  for (int jt = 0; jt < 4; ++jt) {
    int local = wave * 64 + jt * 16 + fm;       // 0..255
    int oo = local >> 5, kip = local & 31;
    size_t jc = (size_t)segbase + (size_t)(o0 + oo) * KIP + kc * 32 + kip;
    f16x8 bf = *(const f16x8*)(pT + jc * 32 + fg * 8);
#pragma unroll
    for (int i = 0; i < 4; ++i)
      acc[i][jt] = __builtin_amdgcn_mfma_f32_16x16x32_f16(af[i], bf, acc[i][jt], 0, 0, 0);
  }
#pragma unroll
  for (int i = 0; i < 4; ++i)
#pragma unroll
    for (int jt = 0; jt < 4; ++jt)
#pragma unroll
      for (int r = 0; r < 4; ++r)
        wbuf[i * 16 + fg * 4 + r][wave * 64 + jt * 16 + fm] = (_Float16)acc[i][jt][r];
  __syncthreads();
  int NCH = KIP >> 5;
  if (fp8) {
    int CHB = O * 32;                  // bytes per chunk
    int sbaseB = (o0 >> 3) * 256;
    for (int idx = threadIdx.x; idx < 64 * 32; idx += 256) {
      int nsub = idx >> 5, w = idx & 31;
      int oo = w & 7;
      int s = (w >> 3) ^ (w & 3);
      int pos = oo * 32 + s * 8;
      const _Float16* v = &wbuf[nsub][pos];
      unsigned d0 = __builtin_amdgcn_cvt_pk_fp8_f32((float)v[0], (float)v[1], 0, 0);
      d0 = __builtin_amdgcn_cvt_pk_fp8_f32((float)v[2], (float)v[3], d0, 1);
      unsigned d1 = __builtin_amdgcn_cvt_pk_fp8_f32((float)v[4], (float)v[5], 0, 0);
      d1 = __builtin_amdgcn_cvt_pk_fp8_f32((float)v[6], (float)v[7], d1, 1);
      size_t dst = ((size_t)(n0 + nsub) * NCH + kc) * CHB + sbaseB + (size_t)w * 8;
      uint2 u; u.x = d0; u.y = d1;
      *(uint2*)((unsigned char*)Wt + dst) = u;
    }
  } else {
    int CH = O * 32;                   // halves per chunk
    int sbase = (o0 >> 3) * 256;
    for (int idx = threadIdx.x; idx < 64 * 32; idx += 256) {
      int nsub = idx >> 5, w = idx & 31;
      int oo = w & 7;
      int s = (w >> 3) ^ (w & 3);
      int pos = oo * 32 + s * 8;
      size_t dst = ((size_t)(n0 + nsub) * NCH + kc) * CH + sbase + (size_t)w * 8;
      *(float4*)((__half*)Wt + dst) = *(float4*)&wbuf[nsub][pos];
    }
  }
}

// ---------------- gemm_nt: Y[1024 x Nc] = Ah @ X (64x64 tile) — prelude Axt ----
__global__ __launch_bounds__(256) void gemm_nt_kernel(
    const __half* __restrict__ Ahg, const __half* __restrict__ X0g,
    const __half* __restrict__ X1g, __half* __restrict__ Yg,
    int Nc, int cstride, int split) {
  __shared__ __align__(16) _Float16 As[64][136];
  __shared__ __align__(16) _Float16 Bs[64][144];
  const _Float16* __restrict__ Ah = (const _Float16*)Ahg;
  _Float16* __restrict__ Y = (_Float16*)Yg;
  int tid = threadIdx.x;
  int row0 = blockIdx.y * 64;
  int col0 = blockIdx.x * 64;
  const _Float16* __restrict__ Xsrc =
      (col0 < split) ? (const _Float16*)X0g : (const _Float16*)X1g;
  int colg = (col0 < split) ? col0 : col0 - split;
  int wave = tid >> 6, lane = tid & 63;
  int wm = wave & 1, wn = wave >> 1;
  int fm = lane & 15, fg = lane >> 4;

  int sr = tid >> 2, sc = (tid & 3) * 32;
  const _Float16* pa = Ah + (size_t)(row0 + sr) * 1024 + sc;
  int kq = tid & 31, cg = tid >> 5;
  int kb = 4 * kq;
  const _Float16* pb = Xsrc + (size_t)kb * cstride + colg + cg * 8;
  int chunk = kq >> 1;
  int kin = (kq & 1) * 4;

  f16x8 ra[4], rb[4];
#pragma unroll
  for (int c = 0; c < 4; ++c) ra[c] = *(const f16x8*)(pa + c * 8);
#pragma unroll
  for (int r = 0; r < 4; ++r) rb[r] = *(const f16x8*)(pb + (size_t)r * cstride);

  f32x4 acc[2][2] = {};
  for (int k0 = 0; k0 < 1024; k0 += 128) {
#pragma unroll
    for (int c = 0; c < 4; ++c) *(f16x8*)&As[sr][sc + c * 8] = ra[c];
#pragma unroll
    for (int i = 0; i < 8; ++i) {
      int c = cg * 8 + i;
      f16x4 p;
      p[0] = rb[0][i]; p[1] = rb[1][i]; p[2] = rb[2][i]; p[3] = rb[3][i];
      *(f16x4*)&Bs[c][((chunk ^ (c & 7)) << 3) + kin] = p;
    }
    __syncthreads();
    if (k0 + 128 < 1024) {
#pragma unroll
      for (int c = 0; c < 4; ++c) ra[c] = *(const f16x8*)(pa + k0 + 128 + c * 8);
#pragma unroll
      for (int r = 0; r < 4; ++r)
        rb[r] = *(const f16x8*)(pb + (size_t)(k0 + 128 + r) * cstride);
    }
#pragma unroll
    for (int kc = 0; kc < 4; ++kc) {
      int ck = kc * 4 + fg;
      f16x8 af[2], bf[2];
#pragma unroll
      for (int i = 0; i < 2; ++i)
        af[i] = *(const f16x8*)&As[wm * 32 + i * 16 + fm][kc * 32 + fg * 8];
#pragma unroll
      for (int j = 0; j < 2; ++j) {
        int cl = wn * 32 + j * 16 + fm;
        bf[j] = *(const f16x8*)&Bs[cl][(ck ^ (cl & 7)) << 3];
      }
#pragma unroll
      for (int i = 0; i < 2; ++i)
#pragma unroll
        for (int j = 0; j < 2; ++j)
          acc[i][j] = __builtin_amdgcn_mfma_f32_16x16x32_f16(af[i], bf[j], acc[i][j], 0, 0, 0);
    }
    __syncthreads();
  }
#pragma unroll
  for (int i = 0; i < 2; ++i) {
#pragma unroll
    for (int j = 0; j < 2; ++j) {
      int col = col0 + wn * 32 + j * 16 + fm;
      int rbase = row0 + wm * 32 + i * 16 + fg * 4;
#pragma unroll
      for (int r = 0; r < 4; ++r)
        Y[(size_t)(rbase + r) * Nc + col] = (_Float16)acc[i][j][r];
    }
  }
}

// ---------------- gemm_nt128: Y = Ah @ X, 64(M) x 128(N) tile, K=128/stage ----------------
__global__ __launch_bounds__(256) void gemm_nt128_kernel(
    const __half* __restrict__ Ahg, const __half* __restrict__ X0g,
    const __half* __restrict__ X1g, __half* __restrict__ Yg,
    int Nc, int cstride, int split) {
  __shared__ __align__(16) _Float16 As[64][136];
  __shared__ __align__(16) _Float16 Bs[128][144];
  const _Float16* __restrict__ Ah = (const _Float16*)Ahg;
  _Float16* __restrict__ Y = (_Float16*)Yg;
  int tid = threadIdx.x;
  int row0 = blockIdx.y * 64;
  int col0 = blockIdx.x * 128;
  const _Float16* __restrict__ Xsrc =
      (col0 < split) ? (const _Float16*)X0g : (const _Float16*)X1g;
  int colg = (col0 < split) ? col0 : col0 - split;
  int wave = tid >> 6, lane = tid & 63;
  int fm = lane & 15, fg = lane >> 4;

  int sr = tid >> 2, sc = (tid & 3) * 32;
  const _Float16* pa = Ah + (size_t)(row0 + sr) * 1024 + sc;
  int kq = tid & 31, cg = tid >> 5;
  int kb = 4 * kq;
  const _Float16* pb = Xsrc + (size_t)kb * cstride + colg + cg * 16;
  int chunk = kq >> 1;
  int kin = (kq & 1) * 4;

  f16x8 ra[4], rb[4][2];
#pragma unroll
  for (int c = 0; c < 4; ++c) ra[c] = *(const f16x8*)(pa + c * 8);
#pragma unroll
  for (int r = 0; r < 4; ++r)
#pragma unroll
    for (int h = 0; h < 2; ++h)
      rb[r][h] = *(const f16x8*)(pb + (size_t)r * cstride + h * 8);

  f32x4 acc[4][2] = {};
  for (int k0 = 0; k0 < 1024; k0 += 128) {
#pragma unroll
    for (int c = 0; c < 4; ++c) *(f16x8*)&As[sr][sc + c * 8] = ra[c];
#pragma unroll
    for (int h = 0; h < 2; ++h)
#pragma unroll
      for (int i = 0; i < 8; ++i) {
        int c = cg * 16 + h * 8 + i;
        f16x4 p;
        p[0] = rb[0][h][i]; p[1] = rb[1][h][i]; p[2] = rb[2][h][i]; p[3] = rb[3][h][i];
        *(f16x4*)&Bs[c][((chunk ^ (c & 7)) << 3) + kin] = p;
      }
    __syncthreads();
    if (k0 + 128 < 1024) {
#pragma unroll
      for (int c = 0; c < 4; ++c) ra[c] = *(const f16x8*)(pa + k0 + 128 + c * 8);
#pragma unroll
      for (int r = 0; r < 4; ++r)
#pragma unroll
        for (int h = 0; h < 2; ++h)
          rb[r][h] = *(const f16x8*)(pb + (size_t)(k0 + 128 + r) * cstride + h * 8);
    }
#pragma unroll
    for (int kc = 0; kc < 4; ++kc) {
      int ck = kc * 4 + fg;
      f16x8 af[4], bf[2];
#pragma unroll
      for (int i = 0; i < 4; ++i)
        af[i] = *(const f16x8*)&As[i * 16 + fm][kc * 32 + fg * 8];
#pragma unroll
      for (int j = 0; j < 2; ++j) {
        int cl = wave * 32 + j * 16 + fm;
        bf[j] = *(const f16x8*)&Bs[cl][(ck ^ (cl & 7)) << 3];
      }
#pragma unroll
      for (int i = 0; i < 4; ++i)
#pragma unroll
        for (int j = 0; j < 2; ++j)
          acc[i][j] = __builtin_amdgcn_mfma_f32_16x16x32_f16(af[i], bf[j], acc[i][j], 0, 0, 0);
    }
    __syncthreads();
  }
#pragma unroll
  for (int i = 0; i < 4; ++i) {
#pragma unroll
    for (int j = 0; j < 2; ++j) {
      int col = col0 + wave * 32 + j * 16 + fm;
      int rbase = row0 + i * 16 + fg * 4;
#pragma unroll
      for (int r = 0; r < 4; ++r)
        Y[(size_t)(rbase + r) * Nc + col] = (_Float16)acc[i][j][r];
    }
  }
}

// ---------------- staging-source helpers (128-col layout: [h|Ah] or [zh|Azh]) -------------
__device__ __forceinline__ f16x8 ld_g0(const __half* __restrict__ h16,
                                       const __half* __restrict__ YBD, int n, int idx) {
  int b = idx >> 4, part = (idx >> 3) & 1, ch = idx & 7;
  const _Float16* s = part ? (const _Float16*)YBD + (size_t)n * 4096 + b * 64 + ch * 8
                           : (const _Float16*)h16 + (size_t)n * 2048 + b * 64 + ch * 8;
  return *(const f16x8*)s;
}
__device__ __forceinline__ f16x8 ld_u0(const __half* __restrict__ zh0,
                                       const __half* __restrict__ YCE, int n, int idx) {
  int b = idx >> 4, part = (idx >> 3) & 1, ch = idx & 7;
  const _Float16* s = part ? (const _Float16*)YCE + (size_t)n * 4096 + 2048 + b * 64 + ch * 8
                           : (const _Float16*)zh0 + (size_t)n * 2048 + b * 64 + ch * 8;
  return *(const f16x8*)s;
}

// ---------------- gate0 body: K=128 (4 fp8 chunks), x/Ax folded into epilogue --------------
// Wn = fp8 chunk-major base for node n; chunk stride 4096 B. Chunks 0,1 pre-issued.
__device__ __forceinline__ void gate0_body(
    _Float16* Xs, float (*xq)[4], unsigned char (*Wb)[4096], int n, int t,
    f16x8 pre0, f16x8 pre1, float2 xv, unsigned axu,
    const unsigned char* Wn, const float* __restrict__ Bg, const float* __restrict__ Wxg,
    const float* __restrict__ h32, __half* __restrict__ zh0, __half* __restrict__ r0) {
  constexpr int STRIDE = 136;
  {
    int b0 = t >> 4, p0 = (t >> 3) & 1, c0 = t & 7;
    *(f16x8*)&Xs[b0 * STRIDE + p0 * 64 + c0 * 8] = pre0;
    int idx = t + 256;
    int b1 = idx >> 4, p1 = (idx >> 3) & 1, c1 = idx & 7;
    *(f16x8*)&Xs[b1 * STRIDE + p1 * 64 + c1 * 8] = pre1;
  }
  if (t < 32) {
    __half2 ah = *(__half2*)&axu;
    float2 af2 = __half22float2(ah);
    xq[t][0] = __half2float(__float2half(xv.x));
    xq[t][1] = __half2float(__float2half(xv.y));
    xq[t][2] = af2.x; xq[t][3] = af2.y;
  }
  int wave = t >> 6, lane = t & 63;
  int fm = lane & 15, fg = lane >> 4;
  f32x4 acc[2][2] = {};
#pragma unroll
  for (int kc = 0; kc < 4; ++kc) {
    if (kc == 0) WAIT_VM1_LG;
    else if (kc < 3) WAIT_VM1;
    else WAIT_VM0;
    BARRIER;
    const unsigned char* wb = Wb[kc & 1];
    f16x8 af[2], bf[2];
#pragma unroll
    for (int i = 0; i < 2; ++i)
      af[i] = *(const f16x8*)&Xs[(i * 16 + fm) * STRIDE + kc * 32 + fg * 8];
#pragma unroll
    for (int j = 0; j < 2; ++j)
      bf[j] = wrd8(wb, wave * 32 + j * 16 + fm, fg);
    WAIT_LG;
    BARRIER;
    if (kc < 2) dma_b4k(Wn + (size_t)(kc + 2) * 4096, Wb[kc & 1], t);
    __builtin_amdgcn_s_setprio(1);
#pragma unroll
    for (int i = 0; i < 2; ++i)
#pragma unroll
      for (int j = 0; j < 2; ++j)
        acc[i][j] = __builtin_amdgcn_mfma_f32_16x16x32_f16(af[i], bf[j], acc[i][j], 0, 0, 0);
    __builtin_amdgcn_s_setprio(0);
  }
  const float* Bn = Bg + n * 128;
  const float* Wx = Wxg + (size_t)n * 512;
#pragma unroll
  for (int j = 0; j < 2; ++j) {
    int o = wave * 32 + j * 16 + fm;
    float bias = Bn[o];
    float w0 = Wx[o], w1 = Wx[128 + o], w2 = Wx[256 + o], w3 = Wx[384 + o];
#pragma unroll
    for (int i = 0; i < 2; ++i)
#pragma unroll
      for (int r = 0; r < 4; ++r) {
        int b = i * 16 + fg * 4 + r;
        float px = acc[i][j][r] + bias +
                   w0 * xq[b][0] + w1 * xq[b][1] + w2 * xq[b][2] + w3 * xq[b][3];
        float s = 1.f / (1.f + __expf(-px));
        size_t base = (size_t)n * 2048 + b * 64;
        if (o < 64) zh0[base + o] = __float2half(s * h32[base + o]);
        else        r0[base + o - 64] = __float2half(s);
      }
  }
}

// ---------------- upd0 body: K=128 (4 fp16 chunks), chunk stride 2048 halves ----------
__device__ __forceinline__ void upd0_body(
    _Float16* Xs, float (*xq)[4], _Float16 (*Wb)[2048], int n, int t,
    f16x8 pre0, f16x8 pre1, float2 xv, unsigned axu,
    const _Float16* Wn, const float* __restrict__ Bu, const float* __restrict__ Wxu,
    const __half* __restrict__ r0, float* __restrict__ h32, __half* __restrict__ h16) {
  constexpr int STRIDE = 136;
  {
    int b0 = t >> 4, p0 = (t >> 3) & 1, c0 = t & 7;
    *(f16x8*)&Xs[b0 * STRIDE + p0 * 64 + c0 * 8] = pre0;
    int idx = t + 256;
    int b1 = idx >> 4, p1 = (idx >> 3) & 1, c1 = idx & 7;
    *(f16x8*)&Xs[b1 * STRIDE + p1 * 64 + c1 * 8] = pre1;
  }
  if (t < 32) {
    __half2 ah = *(__half2*)&axu;
    float2 af2 = __half22float2(ah);
    xq[t][0] = __half2float(__float2half(xv.x));
    xq[t][1] = __half2float(__float2half(xv.y));
    xq[t][2] = af2.x; xq[t][3] = af2.y;
  }
  int wave = t >> 6, lane = t & 63;
  int fm = lane & 15, fg = lane >> 4;
  f32x4 acc[2] = {};
#pragma unroll
  for (int kc = 0; kc < 4; ++kc) {
    if (kc == 0) WAIT_VM1_LG;
    else if (kc < 3) WAIT_VM1;
    else WAIT_VM0;
    BARRIER;
    const _Float16* wb = Wb[kc & 1];
    f16x8 bf = wrd(wb, wave * 16 + fm, fg);
    f16x8 af0 = *(const f16x8*)&Xs[(0 * 16 + fm) * STRIDE + kc * 32 + fg * 8];
    f16x8 af1 = *(const f16x8*)&Xs[(1 * 16 + fm) * STRIDE + kc * 32 + fg * 8];
    WAIT_LG;
    BARRIER;
    if (kc < 2) dma_g64(Wn + (size_t)(kc + 2) * 2048, Wb[kc & 1], t);
    __builtin_amdgcn_s_setprio(1);
    acc[0] = __builtin_amdgcn_mfma_f32_16x16x32_f16(af0, bf, acc[0], 0, 0, 0);
    acc[1] = __builtin_amdgcn_mfma_f32_16x16x32_f16(af1, bf, acc[1], 0, 0, 0);
    __builtin_amdgcn_s_setprio(0);
  }
  int o = wave * 16 + fm;
  float bias = Bu[n * 64 + o];
  const float* Wx = Wxu + (size_t)n * 256;
  float w0 = Wx[o], w1 = Wx[64 + o], w2 = Wx[128 + o], w3 = Wx[192 + o];
#pragma unroll
  for (int i = 0; i < 2; ++i)
#pragma unroll
    for (int r = 0; r < 4; ++r) {
      int b = i * 16 + fg * 4 + r;
      float x = acc[i][r] + bias +
                w0 * xq[b][0] + w1 * xq[b][1] + w2 * xq[b][2] + w3 * xq[b][3];
      x = fminf(fmaxf(x, -15.f), 15.f);
      float e = __expf(2.f * x);
      float hc = (e - 1.f) / (e + 1.f);
      size_t base = (size_t)n * 2048 + b * 64;
      float rr = __half2float(r0[base + o]);
      float hnew = rr * h32[base + o] + (1.f - rr) * hc;
      h32[base + o] = hnew;
      h16[base + o] = __float2half(hnew);
    }
}

// ---------------- standalone gate0 / upd0 (prologue) ----------------
__global__ __launch_bounds__(256) void gate0_kernel(
    const __half* __restrict__ h16, const __half* __restrict__ YBD,
    const float* __restrict__ src, const __half* __restrict__ Axt, int tstep,
    const unsigned char* __restrict__ Wtg, const float* __restrict__ Bg,
    const float* __restrict__ Wxg,
    const float* __restrict__ h32, __half* __restrict__ zh0, __half* __restrict__ r0) {
  __shared__ __align__(16) _Float16 Xs[32 * 136];
  __shared__ __align__(16) unsigned char Wb[2][4096];
  __shared__ float xq[32][4];
  int n = blockIdx.x, t = threadIdx.x;
  const unsigned char* Wn = Wtg + (size_t)n * 16384;  // 4 chunks * 4096 B
  f16x8 p0 = ld_g0(h16, YBD, n, t);
  f16x8 p1 = ld_g0(h16, YBD, n, t + 256);
  float2 xv = {}; unsigned ax = 0;
  if (t < 32) {
    xv = *(const float2*)(src + ((size_t)(t * 12 + tstep) * 1024 + n) * 2);
    ax = *(const unsigned*)((const _Float16*)Axt + (size_t)n * 768 + tstep * 64 + t * 2);
  }
  dma_b4k(Wn, Wb[0], t);
  dma_b4k(Wn + 4096, Wb[1], t);
  gate0_body(Xs, xq, Wb, n, t, p0, p1, xv, ax, Wn, Bg, Wxg, h32, zh0, r0);
}

__global__ __launch_bounds__(256) void upd0_kernel(
    const __half* __restrict__ zh0, const __half* __restrict__ YCE,
    const float* __restrict__ src, const __half* __restrict__ Axt, int tstep,
    const __half* __restrict__ Wtg, const float* __restrict__ Bu,
    const float* __restrict__ Wxu,
    const __half* __restrict__ r0, float* __restrict__ h32, __half* __restrict__ h16) {
  __shared__ __align__(16) _Float16 Xs[32 * 136];
  __shared__ __align__(16) _Float16 Wb[2][2048];
  __shared__ float xq[32][4];
  int n = blockIdx.x, t = threadIdx.x;
  const _Float16* Wn = (const _Float16*)Wtg + (size_t)n * 8192;  // 4 chunks * 2048
  f16x8 p0 = ld_u0(zh0, YCE, n, t);
  f16x8 p1 = ld_u0(zh0, YCE, n, t + 256);
  float2 xv = {}; unsigned ax = 0;
  if (t < 32) {
    xv = *(const float2*)(src + ((size_t)(t * 12 + tstep) * 1024 + n) * 2);
    ax = *(const unsigned*)((const _Float16*)Axt + (size_t)n * 768 + tstep * 64 + t * 2);
  }
  dma_g64(Wn, Wb[0], t);
  dma_g64(Wn + 2048, Wb[1], t);
  upd0_body(Xs, xq, Wb, n, t, p0, p1, xv, ax, Wn, Bu, Wxu, r0, h32, h16);
}

// ---------------- F1: gate1(t) + gate0(t+1), fp8 gate weights ----------------
__global__ __launch_bounds__(256) void gate1_gate0_kernel(
    const __half* __restrict__ h1_16, const __half* __restrict__ h2_16,
    const __half* __restrict__ YBD,
    const unsigned char* __restrict__ WtG1, const float* __restrict__ Bg1,
    const float* __restrict__ h2_32, __half* __restrict__ zh1, __half* __restrict__ r1,
    const float* __restrict__ src, const __half* __restrict__ Axt, int tnext,
    const unsigned char* __restrict__ WtG0, const float* __restrict__ Bg0,
    const float* __restrict__ WxG0,
    const float* __restrict__ h1_32, __half* __restrict__ zh0, __half* __restrict__ r0,
    int do_gate0) {
  constexpr int STRIDE = 264;
  __shared__ __align__(16) _Float16 Xs[32 * STRIDE];
  __shared__ __align__(16) unsigned char Wb[2][4096];
  __shared__ float xq[32][4];
  int n = blockIdx.x;
  int t = threadIdx.x;
  const unsigned char* Wn1 = WtG1 + (size_t)n * 32768;  // 8 chunks * 4096 B
  const unsigned char* Wn0 = WtG0 + (size_t)n * 16384;  // 4 chunks * 4096 B
  // phase-1 staging loads
  f16x8 s1[4];
#pragma unroll
  for (int u = 0; u < 4; ++u) {
    int idx = t + u * 256;
    int b = idx >> 5, q = idx & 31;
    const _Float16* s;
    if (q < 8)       s = (const _Float16*)h1_16 + (size_t)n * 2048 + b * 64 + q * 8;
    else if (q < 16) s = (const _Float16*)h2_16 + (size_t)n * 2048 + b * 64 + (q - 8) * 8;
    else if (q < 24) s = (const _Float16*)YBD + (size_t)n * 4096 + b * 64 + (q - 16) * 8;
    else             s = (const _Float16*)YBD + (size_t)n * 4096 + 2048 + b * 64 + (q - 24) * 8;
    s1[u] = *(const f16x8*)s;
  }
  // phase-2 prefetch (T14)
  f16x8 g0p0 = {}, g0p1 = {}; float2 g0xv = {}; unsigned g0ax = 0;
  if (do_gate0) {
    g0p0 = ld_g0(h1_16, YBD, n, t);
    g0p1 = ld_g0(h1_16, YBD, n, t + 256);
    if (t < 32) {
      g0xv = *(const float2*)(src + ((size_t)(t * 12 + tnext) * 1024 + n) * 2);
      g0ax = *(const unsigned*)((const _Float16*)Axt + (size_t)n * 768 + tnext * 64 + t * 2);
    }
  }
  // phase-1 weight chunks 0,1
  dma_b4k(Wn1, Wb[0], t);
  dma_b4k(Wn1 + 4096, Wb[1], t);
#pragma unroll
  for (int u = 0; u < 4; ++u) {
    int idx = t + u * 256;
    int b = idx >> 5, q = idx & 31;
    *(f16x8*)&Xs[b * STRIDE + q * 8] = s1[u];
  }
  int wave = t >> 6, lane = t & 63;
  int fm = lane & 15, fg = lane >> 4;
  {
    f32x4 acc[2][2] = {};
#pragma unroll
    for (int kc = 0; kc < 8; ++kc) {
      if (kc == 0) WAIT_VM1_LG;
      else if (kc < 7) WAIT_VM1;
      else { if (do_gate0) WAIT_VM1; else WAIT_VM0; }
      BARRIER;
      const unsigned char* wb = Wb[kc & 1];
      f16x8 af[2], bf[2];
#pragma unroll
      for (int i = 0; i < 2; ++i)
        af[i] = *(const f16x8*)&Xs[(i * 16 + fm) * STRIDE + kc * 32 + fg * 8];
#pragma unroll
      for (int j = 0; j < 2; ++j)
        bf[j] = wrd8(wb, wave * 32 + j * 16 + fm, fg);
      WAIT_LG;
      BARRIER;
      if (kc < 6) dma_b4k(Wn1 + (size_t)(kc + 2) * 4096, Wb[kc & 1], t);
      else if (do_gate0) dma_b4k(Wn0 + (size_t)(kc - 6) * 4096, Wb[kc & 1], t);
      __builtin_amdgcn_s_setprio(1);
#pragma unroll
      for (int i = 0; i < 2; ++i)
#pragma unroll
        for (int j = 0; j < 2; ++j)
          acc[i][j] = __builtin_amdgcn_mfma_f32_16x16x32_f16(af[i], bf[j], acc[i][j], 0, 0, 0);
      __builtin_amdgcn_s_setprio(0);
    }
    const float* Bn = Bg1 + n * 128;
#pragma unroll
    for (int j = 0; j < 2; ++j) {
      int o = wave * 32 + j * 16 + fm;
      float bias = Bn[o];
#pragma unroll
      for (int i = 0; i < 2; ++i)
#pragma unroll
        for (int r = 0; r < 4; ++r) {
          int b = i * 16 + fg * 4 + r;
          float s = 1.f / (1.f + __expf(-(acc[i][j][r] + bias)));
          size_t base = (size_t)n * 2048 + b * 64;
          if (o < 64) zh1[base + o] = __float2half(s * h2_32[base + o]);
          else        r1[base + o - 64] = __float2half(s);
        }
    }
  }
  if (!do_gate0) return;
  gate0_body(Xs, xq, Wb, n, t, g0p0, g0p1, g0xv, g0ax, Wn0, Bg0, WxG0, h1_32, zh0, r0);
}

// ---------------- F2: upd1(t) + upd0(t+1), fp16 upd weights ----------------
__global__ __launch_bounds__(256) void upd1_upd0_kernel(
    const __half* __restrict__ h1_16, const __half* __restrict__ zh1,
    const __half* __restrict__ YBD, const __half* __restrict__ YCE,
    const __half* __restrict__ WtU1, const float* __restrict__ Bu1,
    const __half* __restrict__ r1, float* __restrict__ h2_32, __half* __restrict__ h2_16,
    const __half* __restrict__ zh0,
    const float* __restrict__ src, const __half* __restrict__ Axt, int tnext,
    const __half* __restrict__ WtU0, const float* __restrict__ Bu0,
    const float* __restrict__ WxU0,
    const __half* __restrict__ r0, float* __restrict__ h1_32, __half* __restrict__ h1_16w,
    int do_upd0) {
  constexpr int STRIDE = 264;
  __shared__ __align__(16) _Float16 Xs[32 * STRIDE];
  __shared__ __align__(16) _Float16 Wb[2][2048];
  __shared__ float xq[32][4];
  int n = blockIdx.x;
  int t = threadIdx.x;
  const _Float16* Wn1 = (const _Float16*)WtU1 + (size_t)n * 16384;  // 8 chunks * 2048
  const _Float16* Wn0 = (const _Float16*)WtU0 + (size_t)n * 8192;   // 4 chunks * 2048
  // phase-1 staging loads
  f16x8 s1[4];
#pragma unroll
  for (int u = 0; u < 4; ++u) {
    int idx = t + u * 256;
    int b = idx >> 5, q = idx & 31;
    const _Float16* s;
    if (q < 8)       s = (const _Float16*)h1_16 + (size_t)n * 2048 + b * 64 + q * 8;
    else if (q < 16) s = (const _Float16*)zh1 + (size_t)n * 2048 + b * 64 + (q - 8) * 8;
    else if (q < 24) s = (const _Float16*)YBD + (size_t)n * 4096 + b * 64 + (q - 16) * 8;
    else             s = (const _Float16*)YCE + (size_t)n * 4096 + b * 64 + (q - 24) * 8;
    s1[u] = *(const f16x8*)s;
  }
  // phase-2 prefetch (T14)
  f16x8 u0p0 = {}, u0p1 = {}; float2 u0xv = {}; unsigned u0ax = 0;
  if (do_upd0) {
    u0p0 = ld_u0(zh0, YCE, n, t);
    u0p1 = ld_u0(zh0, YCE, n, t + 256);
    if (t < 32) {
      u0xv = *(const float2*)(src + ((size_t)(t * 12 + tnext) * 1024 + n) * 2);
      u0ax = *(const unsigned*)((const _Float16*)Axt + (size_t)n * 768 + tnext * 64 + t * 2);
    }
  }
  // phase-1 weight chunks 0,1
  dma_g64(Wn1, Wb[0], t);
  dma_g64(Wn1 + 2048, Wb[1], t);
#pragma unroll
  for (int u = 0; u < 4; ++u) {
    int idx = t + u * 256;
    int b = idx >> 5, q = idx & 31;
    *(f16x8*)&Xs[b * STRIDE + q * 8] = s1[u];
  }
  int wave = t >> 6, lane = t & 63;
  int fm = lane & 15, fg = lane >> 4;
  {
    f32x4 acc[2] = {};
#pragma unroll
    for (int kc = 0; kc < 8; ++kc) {
      if (kc == 0) WAIT_VM1_LG;
      else if (kc < 7) WAIT_VM1;
      else { if (do_upd0) WAIT_VM1; else WAIT_VM0; }
      BARRIER;
      const _Float16* wb = Wb[kc & 1];
      f16x8 bf = wrd(wb, wave * 16 + fm, fg);
      f16x8 af0 = *(const f16x8*)&Xs[(0 * 16 + fm) * STRIDE + kc * 32 + fg * 8];
      f16x8 af1 = *(const f16x8*)&Xs[(1 * 16 + fm) * STRIDE + kc * 32 + fg * 8];
      WAIT_LG;
      BARRIER;
      if (kc < 6) dma_g64(Wn1 + (size_t)(kc + 2) * 2048, Wb[kc & 1], t);
      else if (do_upd0) dma_g64(Wn0 + (size_t)(kc - 6) * 2048, Wb[kc & 1], t);
      __builtin_amdgcn_s_setprio(1);
      acc[0] = __builtin_amdgcn_mfma_f32_16x16x32_f16(af0, bf, acc[0], 0, 0, 0);
      acc[1] = __builtin_amdgcn_mfma_f32_16x16x32_f16(af1, bf, acc[1], 0, 0, 0);
      __builtin_amdgcn_s_setprio(0);
    }
    int o = wave * 16 + fm;
    float bias = Bu1[n * 64 + o];
#pragma unroll
    for (int i = 0; i < 2; ++i)
#pragma unroll
      for (int r = 0; r < 4; ++r) {
        int b = i * 16 + fg * 4 + r;
        float x = acc[i][r] + bias;
        x = fminf(fmaxf(x, -15.f), 15.f);
        float e = __expf(2.f * x);
        float hc = (e - 1.f) / (e + 1.f);
        size_t base = (size_t)n * 2048 + b * 64;
        float rr = __half2float(r1[base + o]);
        float hnew = rr * h2_32[base + o] + (1.f - rr) * hc;
        h2_32[base + o] = hnew;
        h2_16[base + o] = __float2half(hnew);
      }
  }
  if (!do_upd0) return;
  upd0_body(Xs, xq, Wb, n, t, u0p0, u0p1, u0xv, u0ax, Wn0, Bu0, WxU0, r0, h1_32, h1_16w);
}

// ---------------- out[b,o,n] = h2[n,b,:] . conv_w[o,:] + conv_b[o] ----------------
__global__ void final_conv_kernel(const float* __restrict__ h2, const float* __restrict__ cw,
                                  const float* __restrict__ cb, float* __restrict__ out) {
  int tid = blockIdx.x * 256 + threadIdx.x;
  if (tid >= 32 * 1024) return;
  int n = tid & 1023, b = tid >> 10;
  const float* hp = h2 + ((size_t)n * 32 + b) * 64;
  float hv[64];
#pragma unroll
  for (int i = 0; i < 64; ++i) hv[i] = hp[i];
#pragma unroll
  for (int o = 0; o < 12; ++o) {
    float acc = cb[o];
#pragma unroll
    for (int i = 0; i < 64; ++i) acc += hv[i] * cw[o * 64 + i];
    out[((size_t)b * 12 + o) * 1024 + n] = acc;
  }
}

extern "C" void kernel_launch(void* const* d_in, const int* in_sizes, int n_in,
                              void* d_out, int out_size, void* d_ws, size_t ws_size,
                              hipStream_t stream) {
  const float* src = (const float*)d_in[0];
  const float* E   = (const float*)d_in[1];
  const float* gw0 = (const float*)d_in[2];
  const float* gb0 = (const float*)d_in[3];
  const float* uw0 = (const float*)d_in[4];
  const float* ub0 = (const float*)d_in[5];
  const float* gw1 = (const float*)d_in[6];
  const float* gb1 = (const float*)d_in[7];
  const float* uw1 = (const float*)d_in[8];
  const float* ub1 = (const float*)d_in[9];
  const float* cw  = (const float*)d_in[10];
  const float* cb  = (const float*)d_in[11];
  float* out = (float*)d_out;
  (void)in_sizes; (void)n_in; (void)out_size; (void)ws_size;

  char* base = (char*)d_ws;
  size_t off = 0;
  auto alloc = [&](size_t bytes) -> void* {
    void* p = base + off; off += (bytes + 511) & ~(size_t)511; return p;
  };
  __half* Ah   = (__half*)alloc((size_t)1024 * 1024 * 2);           //   2.1 MB
  unsigned char* WtG0 = (unsigned char*)alloc((size_t)1024 * 16384);//  16.8 MB (fp8, K=128)
  __half* WtU0 = (__half*)alloc((size_t)1024 * 64 * 128 * 2);       //  16.8 MB (fp16, K=128)
  unsigned char* WtG1 = (unsigned char*)alloc((size_t)1024 * 32768);//  33.6 MB (fp8)
  __half* WtU1 = (__half*)alloc((size_t)1024 * 64 * 256 * 2);       //  33.6 MB
  float*  Bg0  = (float*) alloc((size_t)1024 * 128 * 4);
  float*  Bu0  = (float*) alloc((size_t)1024 * 64 * 4);
  float*  Bg1  = (float*) alloc((size_t)1024 * 128 * 4);
  float*  Bu1  = (float*) alloc((size_t)1024 * 64 * 4);
  float*  WxG0 = (float*) alloc((size_t)1024 * 512 * 4);            //   2.1 MB
  float*  WxU0 = (float*) alloc((size_t)1024 * 256 * 4);            //   1.0 MB
  // zero-init region (contiguous): h1_32, h2_32, h1_16, h2_16, YBD  (8388608 floats)
  float*  h1_32 = (float*)alloc((size_t)1024 * 2048 * 4);           //   8.4 MB
  float*  h2_32 = (float*)alloc((size_t)1024 * 2048 * 4);           //   8.4 MB
  __half* h1_16 = (__half*)alloc((size_t)1024 * 2048 * 2);          //   4.2 MB
  __half* h2_16 = (__half*)alloc((size_t)1024 * 2048 * 2);          //   4.2 MB
  __half* YBD  = (__half*)alloc((size_t)1024 * 4096 * 2);           //   8.4 MB [A@h1 | A@h2]
  __half* YCE  = (__half*)alloc((size_t)1024 * 4096 * 2);           //   8.4 MB [A@zh1 | A@zh0]
  __half* zh0  = (__half*)alloc((size_t)1024 * 2048 * 2);           //   4.2 MB
  __half* zh1  = (__half*)alloc((size_t)1024 * 2048 * 2);           //   4.2 MB
  __half* Axt  = (__half*)alloc((size_t)1024 * 768 * 2);            //   1.5 MB (A@x all t)
  __half* r1   = (__half*)alloc((size_t)1024 * 2048 * 2);           //   4.2 MB
  __half* r0   = (__half*)alloc((size_t)1024 * 2048 * 2);           //   4.2 MB
  __half* poolT16 = (__half*)alloc((size_t)73728 * 32 * 2);         //   4.7 MB
  __half* E16  = (__half*)alloc((size_t)1024 * 32 * 2);             //  64 KB
  __half* x16  = (__half*)alloc((size_t)1024 * 768 * 2);            //   1.5 MB
  // total ~172 MB

  // ---- prelude (5 dispatches) ----
  compute_A_kernel<<<1024, 256, 0, stream>>>(E, Ah);
  prelude_misc_kernel<<<13312, 256, 0, stream>>>(E, E16, gb0, ub0, gb1, ub1,
                                                 Bg0, Bu0, Bg1, Bu1,
                                                 src, x16, gw0, uw0, WxG0, WxU0,
                                                 (float4*)h1_32);
  pool_t16_kernel<<<768, 256, 0, stream>>>(gw0, uw0, gw1, uw1, poolT16);
  make_wt_mfma_kernel<<<dim3(288, 16), 256, 0, stream>>>(E16, poolT16, WtG0, WtU0, WtG1, WtU1);
  gemm_nt_kernel<<<dim3(12, 16), 256, 0, stream>>>(Ah, (__half*)x16, (__half*)x16, Axt,
                                                   768, 768, 768);

  // ---- prologue: layer-0 step 0 ----
  gate0_kernel<<<1024, 256, 0, stream>>>(h1_16, YBD, src, Axt, 0, WtG0, Bg0, WxG0,
                                         h1_32, zh0, r0);
  gemm_nt128_kernel<<<dim3(16, 16), 256, 0, stream>>>(Ah, zh0, zh0, YCE + 2048,
                                                      4096, 2048, 2048);  // YE = A@zh0(0)
  upd0_kernel<<<1024, 256, 0, stream>>>(zh0, YCE, src, Axt, 0, WtU0, Bu0, WxU0,
                                        r0, h1_32, h1_16);

  // ---- 12 pipelined iterations (4 dispatches each) ----
  for (int t = 0; t < 12; ++t) {
    int more = (t < 11) ? 1 : 0;
    gemm_nt128_kernel<<<dim3(32, 16), 256, 0, stream>>>(Ah, h1_16, h2_16, YBD,
                                                        4096, 2048, 2048);   // G1
    gate1_gate0_kernel<<<1024, 256, 0, stream>>>(h1_16, h2_16, YBD, WtG1, Bg1, h2_32, zh1, r1,
                                                 src, Axt, t + 1, WtG0, Bg0, WxG0,
                                                 h1_32, zh0, r0, more);       // F1
    gemm_nt128_kernel<<<dim3(32, 16), 256, 0, stream>>>(Ah, zh1, zh0, YCE,
                                                        4096, 2048, 2048);   // G2
    upd1_upd0_kernel<<<1024, 256, 0, stream>>>(h1_16, zh1, YBD, YCE, WtU1, Bu1, r1,
                                               h2_32, h2_16, zh0, src, Axt, t + 1,
                                               WtU0, Bu0, WxU0, r0, h1_32, h1_16, more);  // F2
  }

  final_conv_kernel<<<(32 * 1024 + 255) / 256, 256, 0, stream>>>(h2_32, cw, cb, out);
}